// Round 11
// baseline (601.832 us; speedup 1.0000x reference)
//
#include <hip/hip_runtime.h>

#define B_      2
#define NSU     2076
#define NSV     8940
#define ROWS_SU (B_ * NSU)            // 4152
#define ROWS_ALL (B_ * (NSU + NSV))   // 22032
#define MP_SU   2176
#define MP_SV   8960
#define NB64_SV 140                   // 8960/64
#define NB64_SU 33                    // 2112/64
#define NBX_TOT (2 * NB64_SV + 2 * NB64_SU)   // 346
#define NH1     5                     // conv1 K-split
#define NH2     8                     // conv2 K-split
#define KQ_SV   1792                  // conv1 k-cols per split (64-mult)
#define KQ_SU   448
#define NCH_SV  140                   // abft chunks per sv tile
#define NCH_SU  33                    // written chunks per su tile
#define T_SV    560                   // 16-row tiles per solvent batch
#define T_SU    132
#define TILES_TOT (2 * T_SV + 2 * T_SU)   // 1384
#define PADROWS (TILES_TOT * 16)          // 22144
#define TSZ_SV  ((size_t)16 * MP_SV)      // 143360 elems (140 k64-chunks x 1024)
#define TSZ_SU  ((size_t)16 * MP_SU)      // 34816 elems (34 chunks)
#define SU_BASE_E ((size_t)2 * T_SV * TSZ_SV)   // 160563200
#define NEG_INF (-3.402823466e38f)

typedef __attribute__((ext_vector_type(8))) short bf16x8;
typedef __attribute__((ext_vector_type(4))) float f32x4;

union BF8 { bf16x8 v; unsigned int u[4]; };

#define MFMA16 __builtin_amdgcn_mfma_f32_16x16x32_bf16

__device__ __forceinline__ unsigned short f2bf(float x) {
    unsigned int u = __float_as_uint(x);
    u += 0x7FFFu + ((u >> 16) & 1u);
    return (unsigned short)(u >> 16);
}
__device__ __forceinline__ unsigned int pkbf(float lo, float hi) {
    unsigned int r;
    asm("v_cvt_pk_bf16_f32 %0, %1, %2" : "=v"(r) : "v"(lo), "v"(hi));
    return r;
}

// ---------------- pre: y1t = (x @ W_c1)^T bf16 ; init = x @ W_fc1 + b_fc1 ----------------
__global__ __launch_bounds__(256) void pre_kernel(
    const float* __restrict__ xsu, const float* __restrict__ xsv,
    const float* __restrict__ Wc1, const float* __restrict__ Wfc1,
    const float* __restrict__ bfc1,
    unsigned short* __restrict__ y1t, float* __restrict__ initb)
{
    __shared__ float sWc1[64 * 64];
    __shared__ float sWfc1[64 * 32];
    __shared__ float sb[32];
    const int tid = threadIdx.x;
    for (int i = tid; i < 64 * 64; i += 256) sWc1[i] = Wc1[i];
    for (int i = tid; i < 64 * 32; i += 256) sWfc1[i] = Wfc1[i];
    if (tid < 32) sb[tid] = bfc1[tid];
    __syncthreads();

    const int rid = blockIdx.x * 256 + tid;
    if (rid >= ROWS_ALL) return;

    const float* xrow; unsigned short* yt; int m; size_t MPl;
    if (rid < ROWS_SU) {
        int b = rid / NSU; m = rid - b * NSU;
        xrow = xsu + (size_t)rid * 64;
        yt = y1t + (size_t)b * 64 * MP_SU; MPl = MP_SU;
    } else {
        int r2 = rid - ROWS_SU;
        int b = r2 / NSV; m = r2 - b * NSV;
        xrow = xsv + (size_t)r2 * 64;
        yt = y1t + (size_t)2 * 64 * MP_SU + (size_t)b * 64 * MP_SV; MPl = MP_SV;
    }

    float xr[64];
    #pragma unroll
    for (int f4 = 0; f4 < 16; ++f4) {
        float4 v = ((const float4*)xrow)[f4];
        xr[f4 * 4 + 0] = v.x; xr[f4 * 4 + 1] = v.y;
        xr[f4 * 4 + 2] = v.z; xr[f4 * 4 + 3] = v.w;
    }
    for (int c = 0; c < 64; ++c) {
        float acc = 0.f;
        #pragma unroll
        for (int f = 0; f < 64; ++f) acc += xr[f] * sWc1[f * 64 + c];
        yt[(size_t)c * MPl + m] = f2bf(acc);
    }
    float* ini = initb + (size_t)rid * 32;
    for (int c = 0; c < 32; ++c) {
        float acc = sb[c];
        #pragma unroll
        for (int f = 0; f < 64; ++f) acc += xr[f] * sWfc1[f * 32 + c];
        ini[c] = acc;
    }
}

// ---------------- conv1 partial + fragment-major bf16 adjacency writeback ----------------
// R10 structure, K-split deepened to 5 (occupancy ~= the VGPR-72 cap of 7 blocks/CU).
__global__ __launch_bounds__(256) void conv1p_kernel(
    const float* __restrict__ adj_su, const float* __restrict__ adj_sv,
    const unsigned short* __restrict__ y1t,
    unsigned short* __restrict__ abft,
    float* __restrict__ p1)
{
    const int bid = blockIdx.x;
    const int q = blockIdx.y;
    const int tid = threadIdx.x, lane = tid & 63, wid = tid >> 6;
    int M, MP, row0, tile0, KQ;
    const float* A; const unsigned short* Yt; unsigned short* AbT;
    if (bid < 2 * NB64_SV) {
        int b = bid / NB64_SV, rb = bid - b * NB64_SV;
        M = NSV; MP = MP_SV; KQ = KQ_SV;
        A  = adj_sv + (size_t)b * NSV * NSV;
        Yt = y1t + (size_t)2 * 64 * MP_SU + (size_t)b * 64 * MP_SV;
        row0 = rb * 64; tile0 = b * T_SV + rb * 4;
        AbT = abft + (size_t)(tile0 + wid) * TSZ_SV;
    } else {
        int t = bid - 2 * NB64_SV;
        int b = t / NB64_SU, rb = t - b * NB64_SU;
        M = NSU; MP = MP_SU; KQ = KQ_SU;
        A  = adj_su + (size_t)b * NSU * NSU;
        Yt = y1t + (size_t)b * 64 * MP_SU;
        row0 = rb * 64;
        int tsu = b * T_SU + rb * 4;
        tile0 = 2 * T_SV + tsu;
        AbT = abft + SU_BASE_E + (size_t)(tsu + wid) * TSZ_SU;
    }
    const int kbeg = q * KQ;
    const int kend = (q == NH1 - 1) ? M : (kbeg + KQ);

    const int l15 = lane & 15, kq = lane >> 4;
    const int gr  = row0 + wid * 16 + l15;
    const int grc = (gr < M) ? gr : (M - 1);
    const float* Ap  = A + (size_t)grc * M;
    const float* Apk = Ap + kq * 8;
    const unsigned short* Bp = Yt + (size_t)l15 * MP + kq * 8;
    const size_t MPg = (size_t)16 * MP;

    f32x4 acc0 = {0.f,0.f,0.f,0.f}, acc1 = acc0, acc2 = acc0, acc3 = acc0;

    float4 a0,a1,a2,a3, c0,c1,c2,c3;
    bf16x8 b0,b1,b2,b3,b4,b5,b6,b7, d0,d1,d2,d3,d4,d5,d6,d7;

#define LDA(A0,A1,A2,A3,kc) do { \
    A0 = *(const float4*)(Apk + (kc)); \
    A1 = *(const float4*)(Apk + (kc) + 4); \
    A2 = *(const float4*)(Apk + (kc) + 32); \
    A3 = *(const float4*)(Apk + (kc) + 36); } while (0)
#define LDB(B0,B1,B2,B3,B4,B5,B6,B7,kc) do { \
    B0 = *(const bf16x8*)(Bp + (kc)); \
    B1 = *(const bf16x8*)(Bp + (kc) + 32); \
    B2 = *(const bf16x8*)(Bp + MPg + (kc)); \
    B3 = *(const bf16x8*)(Bp + MPg + (kc) + 32); \
    B4 = *(const bf16x8*)(Bp + 2 * MPg + (kc)); \
    B5 = *(const bf16x8*)(Bp + 2 * MPg + (kc) + 32); \
    B6 = *(const bf16x8*)(Bp + 3 * MPg + (kc)); \
    B7 = *(const bf16x8*)(Bp + 3 * MPg + (kc) + 32); } while (0)
#define CVT(F0,F1,A0,A1,A2,A3) do { \
    F0.u[0] = pkbf(A0.x, A0.y); F0.u[1] = pkbf(A0.z, A0.w); \
    F0.u[2] = pkbf(A1.x, A1.y); F0.u[3] = pkbf(A1.z, A1.w); \
    F1.u[0] = pkbf(A2.x, A2.y); F1.u[1] = pkbf(A2.z, A2.w); \
    F1.u[2] = pkbf(A3.x, A3.y); F1.u[3] = pkbf(A3.z, A3.w); } while (0)
#define STFR(F0,F1,kc) do { \
    unsigned short* sp_ = AbT + ((size_t)((kc) >> 6)) * 1024 + lane * 8; \
    *(bf16x8*)sp_ = F0.v; \
    *(bf16x8*)(sp_ + 512) = F1.v; } while (0)
#define CMP8(F0,F1,B0,B1,B2,B3,B4,B5,B6,B7) do { \
    acc0 = MFMA16(F0.v, B0, acc0, 0, 0, 0); \
    acc1 = MFMA16(F0.v, B2, acc1, 0, 0, 0); \
    acc2 = MFMA16(F0.v, B4, acc2, 0, 0, 0); \
    acc3 = MFMA16(F0.v, B6, acc3, 0, 0, 0); \
    acc0 = MFMA16(F1.v, B1, acc0, 0, 0, 0); \
    acc1 = MFMA16(F1.v, B3, acc1, 0, 0, 0); \
    acc2 = MFMA16(F1.v, B5, acc2, 0, 0, 0); \
    acc3 = MFMA16(F1.v, B7, acc3, 0, 0, 0); } while (0)

    const int klast = kbeg + ((kend - kbeg) & ~63);
    if (klast > kbeg) {
        LDA(a0,a1,a2,a3, kbeg);
        LDB(b0,b1,b2,b3,b4,b5,b6,b7, kbeg);
        int kc = kbeg;
        while (kc + 128 <= klast) {
            LDA(c0,c1,c2,c3, kc + 64);
            LDB(d0,d1,d2,d3,d4,d5,d6,d7, kc + 64);
            { BF8 f0, f1; CVT(f0,f1,a0,a1,a2,a3); STFR(f0,f1,kc);
              CMP8(f0,f1,b0,b1,b2,b3,b4,b5,b6,b7); }
            if (kc + 128 < klast) {
                LDA(a0,a1,a2,a3, kc + 128);
                LDB(b0,b1,b2,b3,b4,b5,b6,b7, kc + 128);
            }
            { BF8 f0, f1; CVT(f0,f1,c0,c1,c2,c3); STFR(f0,f1,kc + 64);
              CMP8(f0,f1,d0,d1,d2,d3,d4,d5,d6,d7); }
            kc += 128;
        }
        if (kc < klast) {
            BF8 f0, f1; CVT(f0,f1,a0,a1,a2,a3); STFR(f0,f1,kc);
            CMP8(f0,f1,b0,b1,b2,b3,b4,b5,b6,b7);
        }
    }
    if (klast < kend) {   // guarded tail (< 64 real cols, zero-padded to 64)
        BF8 f0, f1;
        #pragma unroll
        for (int e = 0; e < 8; e += 2) {
            const int ka = klast + kq * 8 + e;
            const float x0 = (ka      < kend) ? Ap[ka]      : 0.f;
            const float x1 = (ka + 1  < kend) ? Ap[ka + 1]  : 0.f;
            const float y0 = (ka + 32 < kend) ? Ap[ka + 32] : 0.f;
            const float y1 = (ka + 33 < kend) ? Ap[ka + 33] : 0.f;
            f0.u[e >> 1] = pkbf(x0, x1);
            f1.u[e >> 1] = pkbf(y0, y1);
        }
        STFR(f0,f1,klast);
        LDB(b0,b1,b2,b3,b4,b5,b6,b7, klast);
        CMP8(f0,f1,b0,b1,b2,b3,b4,b5,b6,b7);
    }
#undef LDA
#undef LDB
#undef CVT
#undef STFR
#undef CMP8

    float* Pp = p1 + ((size_t)q * TILES_TOT + tile0 + wid) * (16 * 64);
    #pragma unroll
    for (int j = 0; j < 4; ++j) {
        const int r = kq * 4 + j;
        Pp[r * 64 +      l15] = acc0[j];
        Pp[r * 64 + 16 + l15] = acc1[j];
        Pp[r * 64 + 32 + l15] = acc2[j];
        Pp[r * 64 + 48 + l15] = acc3[j];
    }
}

// ---------------- combine1: h = relu(sum_q p1 + bc1); y2t = (h @ Wc2)^T bf16 ------------
__global__ __launch_bounds__(256) void combine1_kernel(
    const float* __restrict__ p1, const float* __restrict__ bc1,
    const float* __restrict__ Wc2g, unsigned short* __restrict__ y2t)
{
    __shared__ float sW[64][32];
    __shared__ float sb[64];
    const int tid = threadIdx.x;
    for (int i = tid; i < 2048; i += 256) sW[i >> 5][i & 31] = Wc2g[i];
    if (tid < 64) sb[tid] = bc1[tid];
    __syncthreads();

    const int pr = blockIdx.x * 64 + (tid & 63);
    const int cq = tid >> 6;
    int m, M, MP; unsigned short* Yo;
    if (pr < 2 * T_SV * 16) {
        int b = pr / (T_SV * 16);
        m = pr - b * (T_SV * 16);
        M = NSV; MP = MP_SV;
        Yo = y2t + (size_t)2 * 32 * MP_SU + (size_t)b * 32 * MP_SV;
    } else {
        int t = pr - 2 * T_SV * 16;
        int b = t / (T_SU * 16);
        m = t - b * (T_SU * 16);
        M = NSU; MP = MP_SU;
        Yo = y2t + (size_t)b * 32 * MP_SU;
    }
    const float* P0 = p1 + (size_t)pr * 64;
    const float* P1 = P0 + (size_t)PADROWS * 64;
    const float* P2 = P1 + (size_t)PADROWS * 64;
    const float* P3 = P2 + (size_t)PADROWS * 64;
    const float* P4 = P3 + (size_t)PADROWS * 64;
    float h[64];
    #pragma unroll
    for (int f4 = 0; f4 < 16; ++f4) {
        float4 u = ((const float4*)P0)[f4];
        float4 v = ((const float4*)P1)[f4];
        float4 w = ((const float4*)P2)[f4];
        float4 z = ((const float4*)P3)[f4];
        float4 y = ((const float4*)P4)[f4];
        h[f4 * 4 + 0] = fmaxf(u.x + v.x + w.x + z.x + y.x + sb[f4 * 4 + 0], 0.f);
        h[f4 * 4 + 1] = fmaxf(u.y + v.y + w.y + z.y + y.y + sb[f4 * 4 + 1], 0.f);
        h[f4 * 4 + 2] = fmaxf(u.z + v.z + w.z + z.z + y.z + sb[f4 * 4 + 2], 0.f);
        h[f4 * 4 + 3] = fmaxf(u.w + v.w + w.w + z.w + y.w + sb[f4 * 4 + 3], 0.f);
    }
    float acc[8] = {0.f,0.f,0.f,0.f,0.f,0.f,0.f,0.f};
    #pragma unroll
    for (int f = 0; f < 64; ++f) {
        const float hv = h[f];
        const float4 w0 = *(const float4*)&sW[f][cq * 8];
        const float4 w1 = *(const float4*)&sW[f][cq * 8 + 4];
        acc[0] += hv * w0.x; acc[1] += hv * w0.y; acc[2] += hv * w0.z; acc[3] += hv * w0.w;
        acc[4] += hv * w1.x; acc[5] += hv * w1.y; acc[6] += hv * w1.z; acc[7] += hv * w1.w;
    }
    if (m < M) {
        #pragma unroll
        for (int j = 0; j < 8; ++j)
            Yo[(size_t)(cq * 8 + j) * MP + m] = f2bf(acc[j]);
    }
}

// ---------------- conv2 partial: dense fragment-major bf16 A reads, K-split 8 ----------
// Block order REVERSED vs conv1p's write order: the most-recently-written abft tiles
// (still L3-resident) are read first -> lower latency -> higher BW at the line cap.
__global__ __launch_bounds__(256) void conv2p_kernel(
    const unsigned short* __restrict__ abft,
    const unsigned short* __restrict__ y2t,
    float* __restrict__ p2)
{
    const int bid = (NBX_TOT - 1) - blockIdx.x;   // reversed traversal
    const int q = blockIdx.y;
    const int tid = threadIdx.x, lane = tid & 63, wid = tid >> 6;
    int MP, tile0, cbeg, cend;
    const unsigned short* Yt; const unsigned short* AbT;
    if (bid < 2 * NB64_SV) {
        int b = bid / NB64_SV, rb = bid - b * NB64_SV;
        MP = MP_SV;
        Yt = y2t + (size_t)2 * 32 * MP_SU + (size_t)b * 32 * MP_SV;
        tile0 = b * T_SV + rb * 4;
        AbT = abft + (size_t)(tile0 + wid) * TSZ_SV;
        cbeg = (q * NCH_SV) >> 3;
        cend = ((q + 1) * NCH_SV) >> 3;
    } else {
        int t = bid - 2 * NB64_SV;
        int b = t / NB64_SU, rb = t - b * NB64_SU;
        MP = MP_SU;
        Yt = y2t + (size_t)b * 32 * MP_SU;
        int tsu = b * T_SU + rb * 4;
        tile0 = 2 * T_SV + tsu;
        AbT = abft + SU_BASE_E + (size_t)(tsu + wid) * TSZ_SU;
        cbeg = (q * NCH_SU) >> 3;
        cend = ((q + 1) * NCH_SU) >> 3;
    }

    const int l15 = lane & 15, kq = lane >> 4;
    const unsigned short* Apl = AbT + (size_t)lane * 8;
    const unsigned short* Bp  = Yt + (size_t)l15 * MP + kq * 8;
    const size_t MPg = (size_t)16 * MP;

    f32x4 acc0 = {0.f,0.f,0.f,0.f}, acc1 = acc0;

    bf16x8 fa0, fa1, fc0, fc1;
    bf16x8 b0,b1,b2,b3, d0,d1,d2,d3;

#define LDA2(F0,F1,ch) do { \
    F0 = *(const bf16x8*)(Apl + (size_t)(ch) * 1024); \
    F1 = *(const bf16x8*)(Apl + (size_t)(ch) * 1024 + 512); } while (0)
#define LDB2(B0,B1,B2,B3,ch) do { \
    const unsigned short* bb = Bp + (size_t)(ch) * 64; \
    B0 = *(const bf16x8*)(bb); \
    B1 = *(const bf16x8*)(bb + 32); \
    B2 = *(const bf16x8*)(bb + MPg); \
    B3 = *(const bf16x8*)(bb + MPg + 32); } while (0)
#define CMP4(F0,F1,B0,B1,B2,B3) do { \
    acc0 = MFMA16(F0, B0, acc0, 0, 0, 0); \
    acc1 = MFMA16(F0, B2, acc1, 0, 0, 0); \
    acc0 = MFMA16(F1, B1, acc0, 0, 0, 0); \
    acc1 = MFMA16(F1, B3, acc1, 0, 0, 0); } while (0)

    if (cbeg < cend) {
        LDA2(fa0, fa1, cbeg);
        LDB2(b0,b1,b2,b3, cbeg);
        int ch = cbeg;
        while (ch + 2 <= cend) {
            LDA2(fc0, fc1, ch + 1);
            LDB2(d0,d1,d2,d3, ch + 1);
            CMP4(fa0, fa1, b0,b1,b2,b3);
            if (ch + 2 < cend) {
                LDA2(fa0, fa1, ch + 2);
                LDB2(b0,b1,b2,b3, ch + 2);
            }
            CMP4(fc0, fc1, d0,d1,d2,d3);
            ch += 2;
        }
        if (ch < cend) {
            CMP4(fa0, fa1, b0,b1,b2,b3);
        }
    }
#undef LDA2
#undef LDB2
#undef CMP4

    float* Pp = p2 + ((size_t)q * TILES_TOT + tile0 + wid) * (16 * 32);
    #pragma unroll
    for (int j = 0; j < 4; ++j) {
        const int r = kq * 4 + j;
        Pp[r * 32 +      l15] = acc0[j];
        Pp[r * 32 + 16 + l15] = acc1[j];
    }
}

// ---------------- combine2: part[tile][c] = max_r (sum_q p2 + bc2 + init) ----------------
__global__ __launch_bounds__(256) void combine2_kernel(
    const float* __restrict__ p2, const float* __restrict__ bc2,
    const float* __restrict__ initb, float* __restrict__ part)
{
    const int idx = blockIdx.x * 256 + threadIdx.x;
    if (idx >= TILES_TOT * 32) return;
    const int gt = idx >> 5, c = idx & 31;
    int m0, M; const float* I;
    if (gt < 2 * T_SV) {
        int b = gt / T_SV;
        m0 = (gt - b * T_SV) * 16;
        M = NSV;
        I = initb + (size_t)ROWS_SU * 32 + (size_t)b * NSV * 32;
    } else {
        int t = gt - 2 * T_SV;
        int b = t / T_SU;
        m0 = (t - b * T_SU) * 16;
        M = NSU;
        I = initb + (size_t)b * NSU * 32;
    }
    const float* Q = p2 + (size_t)gt * 16 * 32 + c;
    const size_t QS = (size_t)TILES_TOT * 16 * 32;
    const float bb = bc2[c];
    float mx = NEG_INF;
    #pragma unroll
    for (int r = 0; r < 16; ++r) {
        const int m = m0 + r;
        if (m < M) {
            float s = bb + I[(size_t)m * 32 + c];
            #pragma unroll
            for (int qq = 0; qq < NH2; ++qq) s += Q[(size_t)qq * QS + r * 32];
            mx = fmaxf(mx, s);
        }
    }
    part[(size_t)gt * 32 + c] = mx;
}

// ---------------- head: pool-reduce + 4-layer MLP ----------------
__global__ __launch_bounds__(128) void head_kernel(
    const float* __restrict__ part,
    const float* __restrict__ Wfc2, const float* __restrict__ bfc2,
    const float* __restrict__ Wfc3, const float* __restrict__ bfc3,
    const float* __restrict__ Wfc4, const float* __restrict__ bfc4,
    const float* __restrict__ Wfc5, const float* __restrict__ bfc5,
    float* __restrict__ out)
{
    __shared__ float d[2][64];
    __shared__ float t1[2][32];
    __shared__ float t2[2][64];
    __shared__ float t3[2][32];
    const int tid = threadIdx.x;

    if (tid < 64) {
        const int b = tid >> 5, c = tid & 31;
        float m = NEG_INF;
        const float* ps = part + (size_t)(2 * T_SV + b * T_SU) * 32 + c;
        for (int i = 0; i < T_SU; ++i) m = fmaxf(m, ps[(size_t)i * 32]);
        d[b][c] = m;
        float m2 = NEG_INF;
        const float* pv = part + (size_t)b * T_SV * 32 + c;
        for (int i = 0; i < T_SV; ++i) m2 = fmaxf(m2, pv[(size_t)i * 32]);
        d[b][32 + c] = m2;
    }
    __syncthreads();
    if (tid < 64) {
        const int b = tid >> 5, c = tid & 31;
        float acc = bfc2[c];
        for (int f = 0; f < 64; ++f) acc += d[b][f] * Wfc2[f * 32 + c];
        t1[b][c] = fmaxf(acc, 0.f);
    }
    __syncthreads();
    {
        const int b = tid >> 6, c = tid & 63;
        float acc = bfc3[c];
        for (int f = 0; f < 32; ++f) acc += t1[b][f] * Wfc3[f * 64 + c];
        t2[b][c] = fmaxf(acc, 0.f);
    }
    __syncthreads();
    if (tid < 64) {
        const int b = tid >> 5, c = tid & 31;
        float acc = bfc4[c];
        for (int f = 0; f < 64; ++f) acc += t2[b][f] * Wfc4[f * 32 + c];
        t3[b][c] = fmaxf(acc, 0.f);
    }
    __syncthreads();
    if (tid < 2) {
        float acc = bfc5[0];
        for (int f = 0; f < 32; ++f) acc += t3[tid][f] * Wfc5[f];
        out[tid] = acc;
    }
}

extern "C" void kernel_launch(void* const* d_in, const int* in_sizes, int n_in,
                              void* d_out, int out_size, void* d_ws, size_t ws_size,
                              hipStream_t stream)
{
    const float* solute_adj   = (const float*)d_in[0];
    const float* solute_meth  = (const float*)d_in[1];
    const float* solvent_meth = (const float*)d_in[2];
    const float* solvent_adj  = (const float*)d_in[3];
    const float* W_fc1 = (const float*)d_in[4];
    const float* b_fc1 = (const float*)d_in[5];
    const float* W_c1  = (const float*)d_in[6];
    const float* b_c1  = (const float*)d_in[7];
    const float* W_c2  = (const float*)d_in[8];
    const float* b_c2  = (const float*)d_in[9];
    const float* W_fc2 = (const float*)d_in[10];
    const float* b_fc2 = (const float*)d_in[11];
    const float* W_fc3 = (const float*)d_in[12];
    const float* b_fc3 = (const float*)d_in[13];
    const float* W_fc4 = (const float*)d_in[14];
    const float* b_fc4 = (const float*)d_in[15];
    const float* W_fc5 = (const float*)d_in[16];
    const float* b_fc5 = (const float*)d_in[17];
    float* out = (float*)d_out;

    // workspace layout (bytes) — ~375 MB total (p1/p2 aliased: disjoint lifetimes)
    char* wsb = (char*)d_ws;
    size_t off = 0;
    unsigned short* y1t = (unsigned short*)(wsb + off); off += 2850816;
    unsigned short* y2t = (unsigned short*)(wsb + off); off += 1425408;
    float* initb        = (float*)(wsb + off);          off += 2820096;
    unsigned short* abft = (unsigned short*)(wsb + off);
    off += (SU_BASE_E + (size_t)2 * T_SU * TSZ_SU) * 2;                      // 339.5 MB
    float* p1           = (float*)(wsb + off);
    float* p2           = p1;   // aliased: p1 dead after combine1, p2 born in conv2p
    off += (size_t)NH1 * PADROWS * 64 * 4;                                   // 28.3 MB
    float* part         = (float*)(wsb + off);          off += (size_t)TILES_TOT * 32 * 4;

    pre_kernel<<<dim3((ROWS_ALL + 255) / 256), dim3(256), 0, stream>>>(
        solute_meth, solvent_meth, W_c1, W_fc1, b_fc1, y1t, initb);

    conv1p_kernel<<<dim3(NBX_TOT, NH1), dim3(256), 0, stream>>>(
        solute_adj, solvent_adj, y1t, abft, p1);

    combine1_kernel<<<dim3(PADROWS / 64), dim3(256), 0, stream>>>(p1, b_c1, W_c2, y2t);

    conv2p_kernel<<<dim3(NBX_TOT, NH2), dim3(256), 0, stream>>>(abft, y2t, p2);

    combine2_kernel<<<dim3((TILES_TOT * 32 + 255) / 256), dim3(256), 0, stream>>>(
        p2, b_c2, initb, part);

    head_kernel<<<dim3(1), dim3(128), 0, stream>>>(
        part, W_fc2, b_fc2, W_fc3, b_fc3, W_fc4, b_fc4, W_fc5, b_fc5, out);
}

// Round 12
// 539.045 us; speedup vs baseline: 1.1165x; 1.1165x over previous
//
#include <hip/hip_runtime.h>

#define B_      2
#define NSU     2076
#define NSV     8940
#define ROWS_SU (B_ * NSU)            // 4152
#define ROWS_ALL (B_ * (NSU + NSV))   // 22032
#define MP_SU   2176
#define MP_SV   8960
#define NB64_SV 140                   // 8960/64
#define NB64_SU 33                    // 2112/64
#define NBX_TOT (2 * NB64_SV + 2 * NB64_SU)   // 346
#define NH1     5                     // conv1 K-split
#define NH2     8                     // conv2 K-split
#define KQ_SV   1792                  // conv1 k-cols per split (64-mult)
#define KQ_SU   448
#define NCH_SV  140                   // k64 chunks per sv entity
#define NCH_SU  33                    // written chunks per su entity
#define T_SV    560                   // 16-row tiles per solvent batch
#define T_SU    132
#define TILES_TOT (2 * T_SV + 2 * T_SU)   // 1384
#define PADROWS (TILES_TOT * 16)          // 22144
#define TSZ_SV  ((size_t)16 * MP_SV)      // 143360 elems (140 k64-chunks x 1024)
#define TSZ_SU  ((size_t)16 * MP_SU)      // 34816 elems (34 chunks)
#define SU_BASE_E ((size_t)2 * T_SV * TSZ_SV)   // 160563200
#define NEG_INF (-3.402823466e38f)

// fragment-major B layouts (element offsets in shorts)
#define Y1F_SV(b) ((size_t)(b) * 140 * 4096)
#define Y1F_SU(b) ((size_t)2 * 140 * 4096 + (size_t)(b) * 34 * 4096)
#define Y2F_SV(b) ((size_t)(b) * 140 * 2048)
#define Y2F_SU(b) ((size_t)2 * 140 * 2048 + (size_t)(b) * 34 * 2048)

typedef __attribute__((ext_vector_type(8))) short bf16x8;
typedef __attribute__((ext_vector_type(4))) float f32x4;

union BF8 { bf16x8 v; unsigned int u[4]; };

#define MFMA16 __builtin_amdgcn_mfma_f32_16x16x32_bf16

__device__ __forceinline__ unsigned short f2bf(float x) {
    unsigned int u = __float_as_uint(x);
    u += 0x7FFFu + ((u >> 16) & 1u);
    return (unsigned short)(u >> 16);
}
__device__ __forceinline__ unsigned int pkbf(float lo, float hi) {
    unsigned int r;
    asm("v_cvt_pk_bf16_f32 %0, %1, %2" : "=v"(r) : "v"(lo), "v"(hi));
    return r;
}

// ---------------- pre: y1tf = frag-major bf16(x @ W_c1) ; init = x @ W_fc1 + b_fc1 ------
__global__ __launch_bounds__(256) void pre_kernel(
    const float* __restrict__ xsu, const float* __restrict__ xsv,
    const float* __restrict__ Wc1, const float* __restrict__ Wfc1,
    const float* __restrict__ bfc1,
    unsigned short* __restrict__ y1tf, float* __restrict__ initb)
{
    __shared__ float sWc1[64 * 64];
    __shared__ float sWfc1[64 * 32];
    __shared__ float sb[32];
    const int tid = threadIdx.x;
    for (int i = tid; i < 64 * 64; i += 256) sWc1[i] = Wc1[i];
    for (int i = tid; i < 64 * 32; i += 256) sWfc1[i] = Wfc1[i];
    if (tid < 32) sb[tid] = bfc1[tid];
    __syncthreads();

    const int rid = blockIdx.x * 256 + tid;
    if (rid >= ROWS_ALL) return;

    const float* xrow; unsigned short* yb; int m;
    if (rid < ROWS_SU) {
        int b = rid / NSU; m = rid - b * NSU;
        xrow = xsu + (size_t)rid * 64;
        yb = y1tf + Y1F_SU(b);
    } else {
        int r2 = rid - ROWS_SU;
        int b = r2 / NSV; m = r2 - b * NSV;
        xrow = xsv + (size_t)r2 * 64;
        yb = y1tf + Y1F_SV(b);
    }

    float xr[64];
    #pragma unroll
    for (int f4 = 0; f4 < 16; ++f4) {
        float4 v = ((const float4*)xrow)[f4];
        xr[f4 * 4 + 0] = v.x; xr[f4 * 4 + 1] = v.y;
        xr[f4 * 4 + 2] = v.z; xr[f4 * 4 + 3] = v.w;
    }
    // frag-major target: elem (m,c) -> chunk(m>>6)*4096 + (c>>4)*1024 + half*512
    //                    + ((c&15) + 16*kqq)*8 + e   [half=(m>>5)&1, kqq=(m>>3)&3, e=m&7]
    {
        const int chunk = m >> 6, half = (m >> 5) & 1, kqq = (m >> 3) & 3, e = m & 7;
        unsigned short* yw = yb + (size_t)chunk * 4096 + half * 512 + e;
        for (int c = 0; c < 64; ++c) {
            float acc = 0.f;
            #pragma unroll
            for (int f = 0; f < 64; ++f) acc += xr[f] * sWc1[f * 64 + c];
            yw[(c >> 4) * 1024 + ((c & 15) + 16 * kqq) * 8] = f2bf(acc);
        }
    }
    float* ini = initb + (size_t)rid * 32;
    for (int c = 0; c < 32; ++c) {
        float acc = sb[c];
        #pragma unroll
        for (int f = 0; f < 64; ++f) acc += xr[f] * sWfc1[f * 32 + c];
        ini[c] = acc;
    }
}

// ---------------- conv1 partial + fragment-major bf16 adjacency writeback ----------------
// B-loads now CONTIGUOUS 1KB bursts from frag-major y1tf (shared across the 4 waves).
__global__ __launch_bounds__(256) void conv1p_kernel(
    const float* __restrict__ adj_su, const float* __restrict__ adj_sv,
    const unsigned short* __restrict__ y1tf,
    unsigned short* __restrict__ abft,
    float* __restrict__ p1)
{
    const int bid = blockIdx.x;
    const int q = blockIdx.y;
    const int tid = threadIdx.x, lane = tid & 63, wid = tid >> 6;
    int M, row0, tile0, KQ;
    const float* A; const unsigned short* Yf; unsigned short* AbT;
    if (bid < 2 * NB64_SV) {
        int b = bid / NB64_SV, rb = bid - b * NB64_SV;
        M = NSV; KQ = KQ_SV;
        A  = adj_sv + (size_t)b * NSV * NSV;
        Yf = y1tf + Y1F_SV(b);
        row0 = rb * 64; tile0 = b * T_SV + rb * 4;
        AbT = abft + (size_t)(tile0 + wid) * TSZ_SV;
    } else {
        int t = bid - 2 * NB64_SV;
        int b = t / NB64_SU, rb = t - b * NB64_SU;
        M = NSU; KQ = KQ_SU;
        A  = adj_su + (size_t)b * NSU * NSU;
        Yf = y1tf + Y1F_SU(b);
        row0 = rb * 64;
        int tsu = b * T_SU + rb * 4;
        tile0 = 2 * T_SV + tsu;
        AbT = abft + SU_BASE_E + (size_t)(tsu + wid) * TSZ_SU;
    }
    const int kbeg = q * KQ;
    const int kend = (q == NH1 - 1) ? M : (kbeg + KQ);

    const int l15 = lane & 15, kq = lane >> 4;
    const int gr  = row0 + wid * 16 + l15;
    const int grc = (gr < M) ? gr : (M - 1);
    const float* Ap  = A + (size_t)grc * M;
    const float* Apk = Ap + kq * 8;
    const unsigned short* Bl = Yf + (size_t)lane * 8;

    f32x4 acc0 = {0.f,0.f,0.f,0.f}, acc1 = acc0, acc2 = acc0, acc3 = acc0;

    float4 a0,a1,a2,a3, c0,c1,c2,c3;
    bf16x8 b0,b1,b2,b3,b4,b5,b6,b7, d0,d1,d2,d3,d4,d5,d6,d7;

#define LDA(A0,A1,A2,A3,kc) do { \
    A0 = *(const float4*)(Apk + (kc)); \
    A1 = *(const float4*)(Apk + (kc) + 4); \
    A2 = *(const float4*)(Apk + (kc) + 32); \
    A3 = *(const float4*)(Apk + (kc) + 36); } while (0)
#define LDB(B0,B1,B2,B3,B4,B5,B6,B7,kc) do { \
    const unsigned short* bb = Bl + ((size_t)((kc) >> 6)) * 4096; \
    B0 = *(const bf16x8*)(bb); \
    B1 = *(const bf16x8*)(bb + 512); \
    B2 = *(const bf16x8*)(bb + 1024); \
    B3 = *(const bf16x8*)(bb + 1536); \
    B4 = *(const bf16x8*)(bb + 2048); \
    B5 = *(const bf16x8*)(bb + 2560); \
    B6 = *(const bf16x8*)(bb + 3072); \
    B7 = *(const bf16x8*)(bb + 3584); } while (0)
#define CVT(F0,F1,A0,A1,A2,A3) do { \
    F0.u[0] = pkbf(A0.x, A0.y); F0.u[1] = pkbf(A0.z, A0.w); \
    F0.u[2] = pkbf(A1.x, A1.y); F0.u[3] = pkbf(A1.z, A1.w); \
    F1.u[0] = pkbf(A2.x, A2.y); F1.u[1] = pkbf(A2.z, A2.w); \
    F1.u[2] = pkbf(A3.x, A3.y); F1.u[3] = pkbf(A3.z, A3.w); } while (0)
#define STFR(F0,F1,kc) do { \
    unsigned short* sp_ = AbT + ((size_t)((kc) >> 6)) * 1024 + lane * 8; \
    *(bf16x8*)sp_ = F0.v; \
    *(bf16x8*)(sp_ + 512) = F1.v; } while (0)
#define CMP8(F0,F1,B0,B1,B2,B3,B4,B5,B6,B7) do { \
    acc0 = MFMA16(F0.v, B0, acc0, 0, 0, 0); \
    acc1 = MFMA16(F0.v, B2, acc1, 0, 0, 0); \
    acc2 = MFMA16(F0.v, B4, acc2, 0, 0, 0); \
    acc3 = MFMA16(F0.v, B6, acc3, 0, 0, 0); \
    acc0 = MFMA16(F1.v, B1, acc0, 0, 0, 0); \
    acc1 = MFMA16(F1.v, B3, acc1, 0, 0, 0); \
    acc2 = MFMA16(F1.v, B5, acc2, 0, 0, 0); \
    acc3 = MFMA16(F1.v, B7, acc3, 0, 0, 0); } while (0)

    const int klast = kbeg + ((kend - kbeg) & ~63);
    if (klast > kbeg) {
        LDA(a0,a1,a2,a3, kbeg);
        LDB(b0,b1,b2,b3,b4,b5,b6,b7, kbeg);
        int kc = kbeg;
        while (kc + 128 <= klast) {
            LDA(c0,c1,c2,c3, kc + 64);
            LDB(d0,d1,d2,d3,d4,d5,d6,d7, kc + 64);
            { BF8 f0, f1; CVT(f0,f1,a0,a1,a2,a3); STFR(f0,f1,kc);
              CMP8(f0,f1,b0,b1,b2,b3,b4,b5,b6,b7); }
            if (kc + 128 < klast) {
                LDA(a0,a1,a2,a3, kc + 128);
                LDB(b0,b1,b2,b3,b4,b5,b6,b7, kc + 128);
            }
            { BF8 f0, f1; CVT(f0,f1,c0,c1,c2,c3); STFR(f0,f1,kc + 64);
              CMP8(f0,f1,d0,d1,d2,d3,d4,d5,d6,d7); }
            kc += 128;
        }
        if (kc < klast) {
            BF8 f0, f1; CVT(f0,f1,a0,a1,a2,a3); STFR(f0,f1,kc);
            CMP8(f0,f1,b0,b1,b2,b3,b4,b5,b6,b7);
        }
    }
    if (klast < kend) {   // guarded tail (< 64 real cols, zero-padded to 64)
        BF8 f0, f1;
        #pragma unroll
        for (int e = 0; e < 8; e += 2) {
            const int ka = klast + kq * 8 + e;
            const float x0 = (ka      < kend) ? Ap[ka]      : 0.f;
            const float x1 = (ka + 1  < kend) ? Ap[ka + 1]  : 0.f;
            const float y0 = (ka + 32 < kend) ? Ap[ka + 32] : 0.f;
            const float y1 = (ka + 33 < kend) ? Ap[ka + 33] : 0.f;
            f0.u[e >> 1] = pkbf(x0, x1);
            f1.u[e >> 1] = pkbf(y0, y1);
        }
        STFR(f0,f1,klast);
        LDB(b0,b1,b2,b3,b4,b5,b6,b7, klast);
        CMP8(f0,f1,b0,b1,b2,b3,b4,b5,b6,b7);
    }
#undef LDA
#undef LDB
#undef CVT
#undef STFR
#undef CMP8

    float* Pp = p1 + ((size_t)q * TILES_TOT + tile0 + wid) * (16 * 64);
    #pragma unroll
    for (int j = 0; j < 4; ++j) {
        const int r = kq * 4 + j;
        Pp[r * 64 +      l15] = acc0[j];
        Pp[r * 64 + 16 + l15] = acc1[j];
        Pp[r * 64 + 32 + l15] = acc2[j];
        Pp[r * 64 + 48 + l15] = acc3[j];
    }
}

// ---------------- combine1: h = relu(sum_q p1 + bc1); y2tf = frag-major bf16(h @ Wc2) ----
__global__ __launch_bounds__(256) void combine1_kernel(
    const float* __restrict__ p1, const float* __restrict__ bc1,
    const float* __restrict__ Wc2g, unsigned short* __restrict__ y2tf)
{
    __shared__ float sW[64][32];
    __shared__ float sb[64];
    const int tid = threadIdx.x;
    for (int i = tid; i < 2048; i += 256) sW[i >> 5][i & 31] = Wc2g[i];
    if (tid < 64) sb[tid] = bc1[tid];
    __syncthreads();

    const int pr = blockIdx.x * 64 + (tid & 63);
    const int cq = tid >> 6;
    int m, M; unsigned short* y2b;
    if (pr < 2 * T_SV * 16) {
        int b = pr / (T_SV * 16);
        m = pr - b * (T_SV * 16);
        M = NSV;
        y2b = y2tf + Y2F_SV(b);
    } else {
        int t = pr - 2 * T_SV * 16;
        int b = t / (T_SU * 16);
        m = t - b * (T_SU * 16);
        M = NSU;
        y2b = y2tf + Y2F_SU(b);
    }
    const float* P0 = p1 + (size_t)pr * 64;
    const float* P1 = P0 + (size_t)PADROWS * 64;
    const float* P2 = P1 + (size_t)PADROWS * 64;
    const float* P3 = P2 + (size_t)PADROWS * 64;
    const float* P4 = P3 + (size_t)PADROWS * 64;
    float h[64];
    #pragma unroll
    for (int f4 = 0; f4 < 16; ++f4) {
        float4 u = ((const float4*)P0)[f4];
        float4 v = ((const float4*)P1)[f4];
        float4 w = ((const float4*)P2)[f4];
        float4 z = ((const float4*)P3)[f4];
        float4 y = ((const float4*)P4)[f4];
        h[f4 * 4 + 0] = fmaxf(u.x + v.x + w.x + z.x + y.x + sb[f4 * 4 + 0], 0.f);
        h[f4 * 4 + 1] = fmaxf(u.y + v.y + w.y + z.y + y.y + sb[f4 * 4 + 1], 0.f);
        h[f4 * 4 + 2] = fmaxf(u.z + v.z + w.z + z.z + y.z + sb[f4 * 4 + 2], 0.f);
        h[f4 * 4 + 3] = fmaxf(u.w + v.w + w.w + z.w + y.w + sb[f4 * 4 + 3], 0.f);
    }
    float acc[8] = {0.f,0.f,0.f,0.f,0.f,0.f,0.f,0.f};
    #pragma unroll
    for (int f = 0; f < 64; ++f) {
        const float hv = h[f];
        const float4 w0 = *(const float4*)&sW[f][cq * 8];
        const float4 w1 = *(const float4*)&sW[f][cq * 8 + 4];
        acc[0] += hv * w0.x; acc[1] += hv * w0.y; acc[2] += hv * w0.z; acc[3] += hv * w0.w;
        acc[4] += hv * w1.x; acc[5] += hv * w1.y; acc[6] += hv * w1.z; acc[7] += hv * w1.w;
    }
    if (m < M) {
        const int chunk = m >> 6, half = (m >> 5) & 1, kqq = (m >> 3) & 3, e = m & 7;
        unsigned short* yw = y2b + (size_t)chunk * 2048 + half * 512 + e;
        #pragma unroll
        for (int j = 0; j < 8; ++j) {
            const int c = cq * 8 + j;
            yw[(c >> 4) * 1024 + ((c & 15) + 16 * kqq) * 8] = f2bf(acc[j]);
        }
    }
}

// ---------------- conv2 partial: BOTH operands dense contiguous frag-major, K-split 8 ----
__global__ __launch_bounds__(256) void conv2p_kernel(
    const unsigned short* __restrict__ abft,
    const unsigned short* __restrict__ y2tf,
    float* __restrict__ p2)
{
    const int bid = (NBX_TOT - 1) - blockIdx.x;   // reversed traversal (L3 tail)
    const int q = blockIdx.y;
    const int tid = threadIdx.x, lane = tid & 63, wid = tid >> 6;
    int tile0, cbeg, cend;
    const unsigned short* Yf2; const unsigned short* AbT;
    if (bid < 2 * NB64_SV) {
        int b = bid / NB64_SV, rb = bid - b * NB64_SV;
        Yf2 = y2tf + Y2F_SV(b);
        tile0 = b * T_SV + rb * 4;
        AbT = abft + (size_t)(tile0 + wid) * TSZ_SV;
        cbeg = (q * NCH_SV) >> 3;
        cend = ((q + 1) * NCH_SV) >> 3;
    } else {
        int t = bid - 2 * NB64_SV;
        int b = t / NB64_SU, rb = t - b * NB64_SU;
        Yf2 = y2tf + Y2F_SU(b);
        int tsu = b * T_SU + rb * 4;
        tile0 = 2 * T_SV + tsu;
        AbT = abft + SU_BASE_E + (size_t)(tsu + wid) * TSZ_SU;
        cbeg = (q * NCH_SU) >> 3;
        cend = ((q + 1) * NCH_SU) >> 3;
    }

    const int l15 = lane & 15, kq = lane >> 4;
    const unsigned short* Apl = AbT + (size_t)lane * 8;
    const unsigned short* Bl  = Yf2 + (size_t)lane * 8;

    f32x4 acc0 = {0.f,0.f,0.f,0.f}, acc1 = acc0;

    bf16x8 fa0, fa1, fc0, fc1;
    bf16x8 b0,b1,b2,b3, d0,d1,d2,d3;

#define LDA2(F0,F1,ch) do { \
    F0 = *(const bf16x8*)(Apl + (size_t)(ch) * 1024); \
    F1 = *(const bf16x8*)(Apl + (size_t)(ch) * 1024 + 512); } while (0)
#define LDB2(B0,B1,B2,B3,ch) do { \
    const unsigned short* bb = Bl + (size_t)(ch) * 2048; \
    B0 = *(const bf16x8*)(bb); \
    B1 = *(const bf16x8*)(bb + 512); \
    B2 = *(const bf16x8*)(bb + 1024); \
    B3 = *(const bf16x8*)(bb + 1536); } while (0)
#define CMP4(F0,F1,B0,B1,B2,B3) do { \
    acc0 = MFMA16(F0, B0, acc0, 0, 0, 0); \
    acc1 = MFMA16(F0, B2, acc1, 0, 0, 0); \
    acc0 = MFMA16(F1, B1, acc0, 0, 0, 0); \
    acc1 = MFMA16(F1, B3, acc1, 0, 0, 0); } while (0)

    if (cbeg < cend) {
        LDA2(fa0, fa1, cbeg);
        LDB2(b0,b1,b2,b3, cbeg);
        int ch = cbeg;
        while (ch + 2 <= cend) {
            LDA2(fc0, fc1, ch + 1);
            LDB2(d0,d1,d2,d3, ch + 1);
            CMP4(fa0, fa1, b0,b1,b2,b3);
            if (ch + 2 < cend) {
                LDA2(fa0, fa1, ch + 2);
                LDB2(b0,b1,b2,b3, ch + 2);
            }
            CMP4(fc0, fc1, d0,d1,d2,d3);
            ch += 2;
        }
        if (ch < cend) {
            CMP4(fa0, fa1, b0,b1,b2,b3);
        }
    }
#undef LDA2
#undef LDB2
#undef CMP4

    float* Pp = p2 + ((size_t)q * TILES_TOT + tile0 + wid) * (16 * 32);
    #pragma unroll
    for (int j = 0; j < 4; ++j) {
        const int r = kq * 4 + j;
        Pp[r * 32 +      l15] = acc0[j];
        Pp[r * 32 + 16 + l15] = acc1[j];
    }
}

// ---------------- combine2: part[tile][c] = max_r (sum_q p2 + bc2 + init) ----------------
__global__ __launch_bounds__(256) void combine2_kernel(
    const float* __restrict__ p2, const float* __restrict__ bc2,
    const float* __restrict__ initb, float* __restrict__ part)
{
    const int idx = blockIdx.x * 256 + threadIdx.x;
    if (idx >= TILES_TOT * 32) return;
    const int gt = idx >> 5, c = idx & 31;
    int m0, M; const float* I;
    if (gt < 2 * T_SV) {
        int b = gt / T_SV;
        m0 = (gt - b * T_SV) * 16;
        M = NSV;
        I = initb + (size_t)ROWS_SU * 32 + (size_t)b * NSV * 32;
    } else {
        int t = gt - 2 * T_SV;
        int b = t / T_SU;
        m0 = (t - b * T_SU) * 16;
        M = NSU;
        I = initb + (size_t)b * NSU * 32;
    }
    const float* Q = p2 + (size_t)gt * 16 * 32 + c;
    const size_t QS = (size_t)TILES_TOT * 16 * 32;
    const float bb = bc2[c];
    float mx = NEG_INF;
    #pragma unroll
    for (int r = 0; r < 16; ++r) {
        const int m = m0 + r;
        if (m < M) {
            float s = bb + I[(size_t)m * 32 + c];
            #pragma unroll
            for (int qq = 0; qq < NH2; ++qq) s += Q[(size_t)qq * QS + r * 32];
            mx = fmaxf(mx, s);
        }
    }
    part[(size_t)gt * 32 + c] = mx;
}

// ---------------- head: pool-reduce + 4-layer MLP ----------------
__global__ __launch_bounds__(128) void head_kernel(
    const float* __restrict__ part,
    const float* __restrict__ Wfc2, const float* __restrict__ bfc2,
    const float* __restrict__ Wfc3, const float* __restrict__ bfc3,
    const float* __restrict__ Wfc4, const float* __restrict__ bfc4,
    const float* __restrict__ Wfc5, const float* __restrict__ bfc5,
    float* __restrict__ out)
{
    __shared__ float d[2][64];
    __shared__ float t1[2][32];
    __shared__ float t2[2][64];
    __shared__ float t3[2][32];
    const int tid = threadIdx.x;

    if (tid < 64) {
        const int b = tid >> 5, c = tid & 31;
        float m = NEG_INF;
        const float* ps = part + (size_t)(2 * T_SV + b * T_SU) * 32 + c;
        for (int i = 0; i < T_SU; ++i) m = fmaxf(m, ps[(size_t)i * 32]);
        d[b][c] = m;
        float m2 = NEG_INF;
        const float* pv = part + (size_t)b * T_SV * 32 + c;
        for (int i = 0; i < T_SV; ++i) m2 = fmaxf(m2, pv[(size_t)i * 32]);
        d[b][32 + c] = m2;
    }
    __syncthreads();
    if (tid < 64) {
        const int b = tid >> 5, c = tid & 31;
        float acc = bfc2[c];
        for (int f = 0; f < 64; ++f) acc += d[b][f] * Wfc2[f * 32 + c];
        t1[b][c] = fmaxf(acc, 0.f);
    }
    __syncthreads();
    {
        const int b = tid >> 6, c = tid & 63;
        float acc = bfc3[c];
        for (int f = 0; f < 32; ++f) acc += t1[b][f] * Wfc3[f * 64 + c];
        t2[b][c] = fmaxf(acc, 0.f);
    }
    __syncthreads();
    if (tid < 64) {
        const int b = tid >> 5, c = tid & 31;
        float acc = bfc4[c];
        for (int f = 0; f < 64; ++f) acc += t2[b][f] * Wfc4[f * 32 + c];
        t3[b][c] = fmaxf(acc, 0.f);
    }
    __syncthreads();
    if (tid < 2) {
        float acc = bfc5[0];
        for (int f = 0; f < 32; ++f) acc += t3[tid][f] * Wfc5[f];
        out[tid] = acc;
    }
}

extern "C" void kernel_launch(void* const* d_in, const int* in_sizes, int n_in,
                              void* d_out, int out_size, void* d_ws, size_t ws_size,
                              hipStream_t stream)
{
    const float* solute_adj   = (const float*)d_in[0];
    const float* solute_meth  = (const float*)d_in[1];
    const float* solvent_meth = (const float*)d_in[2];
    const float* solvent_adj  = (const float*)d_in[3];
    const float* W_fc1 = (const float*)d_in[4];
    const float* b_fc1 = (const float*)d_in[5];
    const float* W_c1  = (const float*)d_in[6];
    const float* b_c1  = (const float*)d_in[7];
    const float* W_c2  = (const float*)d_in[8];
    const float* b_c2  = (const float*)d_in[9];
    const float* W_fc2 = (const float*)d_in[10];
    const float* b_fc2 = (const float*)d_in[11];
    const float* W_fc3 = (const float*)d_in[12];
    const float* b_fc3 = (const float*)d_in[13];
    const float* W_fc4 = (const float*)d_in[14];
    const float* b_fc4 = (const float*)d_in[15];
    const float* W_fc5 = (const float*)d_in[16];
    const float* b_fc5 = (const float*)d_in[17];
    float* out = (float*)d_out;

    // workspace layout (bytes) — ~375 MB total (p1/p2 aliased: disjoint lifetimes)
    char* wsb = (char*)d_ws;
    size_t off = 0;
    unsigned short* y1tf = (unsigned short*)(wsb + off); off += 2850816;  // frag-major
    unsigned short* y2tf = (unsigned short*)(wsb + off); off += 1425408;  // frag-major
    float* initb         = (float*)(wsb + off);          off += 2820096;
    unsigned short* abft = (unsigned short*)(wsb + off);
    off += (SU_BASE_E + (size_t)2 * T_SU * TSZ_SU) * 2;                   // 339.5 MB
    float* p1            = (float*)(wsb + off);
    float* p2            = p1;   // aliased: p1 dead after combine1
    off += (size_t)NH1 * PADROWS * 64 * 4;                                // 28.3 MB
    float* part          = (float*)(wsb + off);          off += (size_t)TILES_TOT * 32 * 4;

    pre_kernel<<<dim3((ROWS_ALL + 255) / 256), dim3(256), 0, stream>>>(
        solute_meth, solvent_meth, W_c1, W_fc1, b_fc1, y1tf, initb);

    conv1p_kernel<<<dim3(NBX_TOT, NH1), dim3(256), 0, stream>>>(
        solute_adj, solvent_adj, y1tf, abft, p1);

    combine1_kernel<<<dim3(PADROWS / 64), dim3(256), 0, stream>>>(p1, b_c1, W_c2, y2tf);

    conv2p_kernel<<<dim3(NBX_TOT, NH2), dim3(256), 0, stream>>>(abft, y2tf, p2);

    combine2_kernel<<<dim3((TILES_TOT * 32 + 255) / 256), dim3(256), 0, stream>>>(
        p2, b_c2, initb, part);

    head_kernel<<<dim3(1), dim3(128), 0, stream>>>(
        part, W_fc2, b_fc2, W_fc3, b_fc3, W_fc4, b_fc4, W_fc5, b_fc5, out);
}

// Round 14
// 471.841 us; speedup vs baseline: 1.2755x; 1.1424x over previous
//
#include <hip/hip_runtime.h>

#define B_      2
#define NSU     2076
#define NSV     8940
#define ROWS_SU (B_ * NSU)            // 4152
#define ROWS_ALL (B_ * (NSU + NSV))   // 22032
#define MP_SU   2176
#define MP_SV   8960
#define NB64_SV 140                   // 8960/64
#define NB64_SU 33                    // 2112/64
#define NBX_TOT (2 * NB64_SV + 2 * NB64_SU)   // 346
#define NH1     5                     // conv1 K-split
#define NH2     8                     // conv2 K-split
#define KQ_SV   1792                  // conv1 k-cols per split (64-mult)
#define KQ_SU   448
#define NCH_SV  140                   // k64 chunks per sv entity
#define NCH_SU  33                    // written chunks per su entity
#define T_SV    560                   // 16-row tiles per solvent batch
#define T_SU    132
#define TILES_TOT (2 * T_SV + 2 * T_SU)   // 1384
#define PADROWS (TILES_TOT * 16)          // 22144
// fp8 adjacency: 1024 bytes per k64 chunk per tile
#define TSZ8_SV ((size_t)140 * 1024)
#define TSZ8_SU ((size_t)34 * 1024)
#define SU_BASE8 ((size_t)2 * T_SV * TSZ8_SV)   // 160563200 bytes
#define NEG_INF (-3.402823466e38f)

// frag-major layouts (y1 bf16 elems; y2 fp8 bytes)
#define Y1F_SV(b) ((size_t)(b) * 140 * 4096)
#define Y1F_SU(b) ((size_t)2 * 140 * 4096 + (size_t)(b) * 34 * 4096)
#define Y2F8_SV(b) ((size_t)(b) * 140 * 2048)
#define Y2F8_SU(b) ((size_t)2 * 140 * 2048 + (size_t)(b) * 34 * 2048)

typedef __attribute__((ext_vector_type(8))) short bf16x8;
typedef __attribute__((ext_vector_type(4))) float f32x4;
typedef __attribute__((ext_vector_type(2))) long longx2;

union BF8 { bf16x8 v; unsigned int u[4]; };

#define MFMA16 __builtin_amdgcn_mfma_f32_16x16x32_bf16
#define MFMA8  __builtin_amdgcn_mfma_f32_16x16x32_fp8_fp8

__device__ __forceinline__ unsigned short f2bf(float x) {
    unsigned int u = __float_as_uint(x);
    u += 0x7FFFu + ((u >> 16) & 1u);
    return (unsigned short)(u >> 16);
}
__device__ __forceinline__ unsigned int pkbf(float lo, float hi) {
    unsigned int r;
    asm("v_cvt_pk_bf16_f32 %0, %1, %2" : "=v"(r) : "v"(lo), "v"(hi));
    return r;
}
// word-select must be a compile-time constant -> two wrappers
__device__ __forceinline__ int pk8lo(float lo, float hi, int old) {
    return __builtin_amdgcn_cvt_pk_fp8_f32(lo, hi, old, false);
}
__device__ __forceinline__ int pk8hi(float lo, float hi, int old) {
    return __builtin_amdgcn_cvt_pk_fp8_f32(lo, hi, old, true);
}

// ---------------- pre: y1tf = frag-major bf16(x @ W_c1) ; init = x @ W_fc1 + b_fc1 ------
__global__ __launch_bounds__(256) void pre_kernel(
    const float* __restrict__ xsu, const float* __restrict__ xsv,
    const float* __restrict__ Wc1, const float* __restrict__ Wfc1,
    const float* __restrict__ bfc1,
    unsigned short* __restrict__ y1tf, float* __restrict__ initb)
{
    __shared__ float sWc1[64 * 64];
    __shared__ float sWfc1[64 * 32];
    __shared__ float sb[32];
    const int tid = threadIdx.x;
    for (int i = tid; i < 64 * 64; i += 256) sWc1[i] = Wc1[i];
    for (int i = tid; i < 64 * 32; i += 256) sWfc1[i] = Wfc1[i];
    if (tid < 32) sb[tid] = bfc1[tid];
    __syncthreads();

    const int rid = blockIdx.x * 256 + tid;
    if (rid >= ROWS_ALL) return;

    const float* xrow; unsigned short* yb; int m;
    if (rid < ROWS_SU) {
        int b = rid / NSU; m = rid - b * NSU;
        xrow = xsu + (size_t)rid * 64;
        yb = y1tf + Y1F_SU(b);
    } else {
        int r2 = rid - ROWS_SU;
        int b = r2 / NSV; m = r2 - b * NSV;
        xrow = xsv + (size_t)r2 * 64;
        yb = y1tf + Y1F_SV(b);
    }

    float xr[64];
    #pragma unroll
    for (int f4 = 0; f4 < 16; ++f4) {
        float4 v = ((const float4*)xrow)[f4];
        xr[f4 * 4 + 0] = v.x; xr[f4 * 4 + 1] = v.y;
        xr[f4 * 4 + 2] = v.z; xr[f4 * 4 + 3] = v.w;
    }
    {
        const int chunk = m >> 6, half = (m >> 5) & 1, kqq = (m >> 3) & 3, e = m & 7;
        unsigned short* yw = yb + (size_t)chunk * 4096 + half * 512 + e;
        for (int c = 0; c < 64; ++c) {
            float acc = 0.f;
            #pragma unroll
            for (int f = 0; f < 64; ++f) acc += xr[f] * sWc1[f * 64 + c];
            yw[(c >> 4) * 1024 + ((c & 15) + 16 * kqq) * 8] = f2bf(acc);
        }
    }
    float* ini = initb + (size_t)rid * 32;
    for (int c = 0; c < 32; ++c) {
        float acc = sb[c];
        #pragma unroll
        for (int f = 0; f < 64; ++f) acc += xr[f] * sWfc1[f * 32 + c];
        ini[c] = acc;
    }
}

// ---------------- conv1 partial + fragment-major FP8 adjacency writeback ----------------
__global__ __launch_bounds__(256) void conv1p_kernel(
    const float* __restrict__ adj_su, const float* __restrict__ adj_sv,
    const unsigned short* __restrict__ y1tf,
    unsigned char* __restrict__ abf8,
    float* __restrict__ p1)
{
    const int bid = blockIdx.x;
    const int q = blockIdx.y;
    const int tid = threadIdx.x, lane = tid & 63, wid = tid >> 6;
    int M, row0, tile0, KQ;
    const float* A; const unsigned short* Yf; unsigned char* AbT;
    if (bid < 2 * NB64_SV) {
        int b = bid / NB64_SV, rb = bid - b * NB64_SV;
        M = NSV; KQ = KQ_SV;
        A  = adj_sv + (size_t)b * NSV * NSV;
        Yf = y1tf + Y1F_SV(b);
        row0 = rb * 64; tile0 = b * T_SV + rb * 4;
        AbT = abf8 + (size_t)(tile0 + wid) * TSZ8_SV;
    } else {
        int t = bid - 2 * NB64_SV;
        int b = t / NB64_SU, rb = t - b * NB64_SU;
        M = NSU; KQ = KQ_SU;
        A  = adj_su + (size_t)b * NSU * NSU;
        Yf = y1tf + Y1F_SU(b);
        row0 = rb * 64;
        int tsu = b * T_SU + rb * 4;
        tile0 = 2 * T_SV + tsu;
        AbT = abf8 + SU_BASE8 + (size_t)(tsu + wid) * TSZ8_SU;
    }
    const int kbeg = q * KQ;
    const int kend = (q == NH1 - 1) ? M : (kbeg + KQ);

    const int l15 = lane & 15, kq = lane >> 4;
    const int gr  = row0 + wid * 16 + l15;
    const int grc = (gr < M) ? gr : (M - 1);
    const float* Ap  = A + (size_t)grc * M;
    const float* Apk = Ap + kq * 8;
    const unsigned short* Bl = Yf + (size_t)lane * 8;

    f32x4 acc0 = {0.f,0.f,0.f,0.f}, acc1 = acc0, acc2 = acc0, acc3 = acc0;

    float4 a0,a1,a2,a3, c0,c1,c2,c3;
    bf16x8 b0,b1,b2,b3,b4,b5,b6,b7, d0,d1,d2,d3,d4,d5,d6,d7;

#define LDA(A0,A1,A2,A3,kc) do { \
    A0 = *(const float4*)(Apk + (kc)); \
    A1 = *(const float4*)(Apk + (kc) + 4); \
    A2 = *(const float4*)(Apk + (kc) + 32); \
    A3 = *(const float4*)(Apk + (kc) + 36); } while (0)
#define LDB(B0,B1,B2,B3,B4,B5,B6,B7,kc) do { \
    const unsigned short* bb = Bl + ((size_t)((kc) >> 6)) * 4096; \
    B0 = *(const bf16x8*)(bb); \
    B1 = *(const bf16x8*)(bb + 512); \
    B2 = *(const bf16x8*)(bb + 1024); \
    B3 = *(const bf16x8*)(bb + 1536); \
    B4 = *(const bf16x8*)(bb + 2048); \
    B5 = *(const bf16x8*)(bb + 2560); \
    B6 = *(const bf16x8*)(bb + 3072); \
    B7 = *(const bf16x8*)(bb + 3584); } while (0)
#define CVT(F0,F1,A0,A1,A2,A3) do { \
    F0.u[0] = pkbf(A0.x, A0.y); F0.u[1] = pkbf(A0.z, A0.w); \
    F0.u[2] = pkbf(A1.x, A1.y); F0.u[3] = pkbf(A1.z, A1.w); \
    F1.u[0] = pkbf(A2.x, A2.y); F1.u[1] = pkbf(A2.z, A2.w); \
    F1.u[2] = pkbf(A3.x, A3.y); F1.u[3] = pkbf(A3.z, A3.w); } while (0)
#define STF8(A0,A1,A2,A3,kc) do { \
    int q0 = pk8lo(A0.x, A0.y, 0); q0 = pk8hi(A0.z, A0.w, q0); \
    int q1 = pk8lo(A1.x, A1.y, 0); q1 = pk8hi(A1.z, A1.w, q1); \
    int q2 = pk8lo(A2.x, A2.y, 0); q2 = pk8hi(A2.z, A2.w, q2); \
    int q3 = pk8lo(A3.x, A3.y, 0); q3 = pk8hi(A3.z, A3.w, q3); \
    *(int4*)(AbT + ((size_t)((kc) >> 6)) * 1024 + lane * 16) = make_int4(q0, q1, q2, q3); } while (0)
#define CMP8(F0,F1,B0,B1,B2,B3,B4,B5,B6,B7) do { \
    acc0 = MFMA16(F0.v, B0, acc0, 0, 0, 0); \
    acc1 = MFMA16(F0.v, B2, acc1, 0, 0, 0); \
    acc2 = MFMA16(F0.v, B4, acc2, 0, 0, 0); \
    acc3 = MFMA16(F0.v, B6, acc3, 0, 0, 0); \
    acc0 = MFMA16(F1.v, B1, acc0, 0, 0, 0); \
    acc1 = MFMA16(F1.v, B3, acc1, 0, 0, 0); \
    acc2 = MFMA16(F1.v, B5, acc2, 0, 0, 0); \
    acc3 = MFMA16(F1.v, B7, acc3, 0, 0, 0); } while (0)

    const int klast = kbeg + ((kend - kbeg) & ~63);
    if (klast > kbeg) {
        LDA(a0,a1,a2,a3, kbeg);
        LDB(b0,b1,b2,b3,b4,b5,b6,b7, kbeg);
        int kc = kbeg;
        while (kc + 128 <= klast) {
            LDA(c0,c1,c2,c3, kc + 64);
            LDB(d0,d1,d2,d3,d4,d5,d6,d7, kc + 64);
            { BF8 f0, f1; CVT(f0,f1,a0,a1,a2,a3); STF8(a0,a1,a2,a3,kc);
              CMP8(f0,f1,b0,b1,b2,b3,b4,b5,b6,b7); }
            if (kc + 128 < klast) {
                LDA(a0,a1,a2,a3, kc + 128);
                LDB(b0,b1,b2,b3,b4,b5,b6,b7, kc + 128);
            }
            { BF8 f0, f1; CVT(f0,f1,c0,c1,c2,c3); STF8(c0,c1,c2,c3,kc + 64);
              CMP8(f0,f1,d0,d1,d2,d3,d4,d5,d6,d7); }
            kc += 128;
        }
        if (kc < klast) {
            BF8 f0, f1; CVT(f0,f1,a0,a1,a2,a3); STF8(a0,a1,a2,a3,kc);
            CMP8(f0,f1,b0,b1,b2,b3,b4,b5,b6,b7);
        }
    }
    if (klast < kend) {   // guarded tail (< 64 real cols, zero-padded to 64)
        BF8 f0, f1;
        float xs[8], ys[8];
        #pragma unroll
        for (int e = 0; e < 8; ++e) {
            const int ka = klast + kq * 8 + e;
            xs[e] = (ka      < kend) ? Ap[ka]      : 0.f;
            ys[e] = (ka + 32 < kend) ? Ap[ka + 32] : 0.f;
        }
        #pragma unroll
        for (int e = 0; e < 8; e += 2) {
            f0.u[e >> 1] = pkbf(xs[e], xs[e + 1]);
            f1.u[e >> 1] = pkbf(ys[e], ys[e + 1]);
        }
        int q0 = pk8lo(xs[0], xs[1], 0); q0 = pk8hi(xs[2], xs[3], q0);
        int q1 = pk8lo(xs[4], xs[5], 0); q1 = pk8hi(xs[6], xs[7], q1);
        int q2 = pk8lo(ys[0], ys[1], 0); q2 = pk8hi(ys[2], ys[3], q2);
        int q3 = pk8lo(ys[4], ys[5], 0); q3 = pk8hi(ys[6], ys[7], q3);
        *(int4*)(AbT + ((size_t)(klast >> 6)) * 1024 + lane * 16) = make_int4(q0, q1, q2, q3);
        LDB(b0,b1,b2,b3,b4,b5,b6,b7, klast);
        CMP8(f0,f1,b0,b1,b2,b3,b4,b5,b6,b7);
    }
#undef LDA
#undef LDB
#undef CVT
#undef STF8
#undef CMP8

    float* Pp = p1 + ((size_t)q * TILES_TOT + tile0 + wid) * (16 * 64);
    #pragma unroll
    for (int j = 0; j < 4; ++j) {
        const int r = kq * 4 + j;
        Pp[r * 64 +      l15] = acc0[j];
        Pp[r * 64 + 16 + l15] = acc1[j];
        Pp[r * 64 + 32 + l15] = acc2[j];
        Pp[r * 64 + 48 + l15] = acc3[j];
    }
}

// ---------------- combine1: h = relu(sum_q p1 + bc1); y2f8 = frag-major fp8(h @ Wc2) ----
__global__ __launch_bounds__(256) void combine1_kernel(
    const float* __restrict__ p1, const float* __restrict__ bc1,
    const float* __restrict__ Wc2g, unsigned char* __restrict__ y2f8)
{
    __shared__ float sW[64][32];
    __shared__ float sb[64];
    const int tid = threadIdx.x;
    for (int i = tid; i < 2048; i += 256) sW[i >> 5][i & 31] = Wc2g[i];
    if (tid < 64) sb[tid] = bc1[tid];
    __syncthreads();

    const int pr = blockIdx.x * 64 + (tid & 63);
    const int cq = tid >> 6;
    int m, M; unsigned char* y2b;
    if (pr < 2 * T_SV * 16) {
        int b = pr / (T_SV * 16);
        m = pr - b * (T_SV * 16);
        M = NSV;
        y2b = y2f8 + Y2F8_SV(b);
    } else {
        int t = pr - 2 * T_SV * 16;
        int b = t / (T_SU * 16);
        m = t - b * (T_SU * 16);
        M = NSU;
        y2b = y2f8 + Y2F8_SU(b);
    }
    const float* P0 = p1 + (size_t)pr * 64;
    const float* P1 = P0 + (size_t)PADROWS * 64;
    const float* P2 = P1 + (size_t)PADROWS * 64;
    const float* P3 = P2 + (size_t)PADROWS * 64;
    const float* P4 = P3 + (size_t)PADROWS * 64;
    float h[64];
    #pragma unroll
    for (int f4 = 0; f4 < 16; ++f4) {
        float4 u = ((const float4*)P0)[f4];
        float4 v = ((const float4*)P1)[f4];
        float4 w = ((const float4*)P2)[f4];
        float4 z = ((const float4*)P3)[f4];
        float4 y = ((const float4*)P4)[f4];
        h[f4 * 4 + 0] = fmaxf(u.x + v.x + w.x + z.x + y.x + sb[f4 * 4 + 0], 0.f);
        h[f4 * 4 + 1] = fmaxf(u.y + v.y + w.y + z.y + y.y + sb[f4 * 4 + 1], 0.f);
        h[f4 * 4 + 2] = fmaxf(u.z + v.z + w.z + z.z + y.z + sb[f4 * 4 + 2], 0.f);
        h[f4 * 4 + 3] = fmaxf(u.w + v.w + w.w + z.w + y.w + sb[f4 * 4 + 3], 0.f);
    }
    float acc[8] = {0.f,0.f,0.f,0.f,0.f,0.f,0.f,0.f};
    #pragma unroll
    for (int f = 0; f < 64; ++f) {
        const float hv = h[f];
        const float4 w0 = *(const float4*)&sW[f][cq * 8];
        const float4 w1 = *(const float4*)&sW[f][cq * 8 + 4];
        acc[0] += hv * w0.x; acc[1] += hv * w0.y; acc[2] += hv * w0.z; acc[3] += hv * w0.w;
        acc[4] += hv * w1.x; acc[5] += hv * w1.y; acc[6] += hv * w1.z; acc[7] += hv * w1.w;
    }
    if (m < M) {
        const int chunk = m >> 6, half = (m >> 5) & 1, kqq = (m >> 3) & 3, e = m & 7;
        unsigned char* yw = y2b + (size_t)chunk * 2048 + half * 8 + e;
        #pragma unroll
        for (int j = 0; j < 8; ++j) {
            const int c = cq * 8 + j;
            const int pk = pk8lo(acc[j], acc[j], 0);
            yw[(c >> 4) * 1024 + (kqq * 16 + (c & 15)) * 16] = (unsigned char)(pk & 0xff);
        }
    }
}

// ---------------- conv2 partial: FP8 MFMA, both operands dense frag-major ---------------
__global__ __launch_bounds__(256) void conv2p_kernel(
    const unsigned char* __restrict__ abf8,
    const unsigned char* __restrict__ y2f8,
    float* __restrict__ p2)
{
    const int bid = (NBX_TOT - 1) - blockIdx.x;   // reversed traversal
    const int q = blockIdx.y;
    const int tid = threadIdx.x, lane = tid & 63, wid = tid >> 6;
    int tile0, cbeg, cend;
    const unsigned char* Yf2; const unsigned char* AbT;
    if (bid < 2 * NB64_SV) {
        int b = bid / NB64_SV, rb = bid - b * NB64_SV;
        Yf2 = y2f8 + Y2F8_SV(b);
        tile0 = b * T_SV + rb * 4;
        AbT = abf8 + (size_t)(tile0 + wid) * TSZ8_SV;
        cbeg = (q * NCH_SV) >> 3;
        cend = ((q + 1) * NCH_SV) >> 3;
    } else {
        int t = bid - 2 * NB64_SV;
        int b = t / NB64_SU, rb = t - b * NB64_SU;
        Yf2 = y2f8 + Y2F8_SU(b);
        int tsu = b * T_SU + rb * 4;
        tile0 = 2 * T_SV + tsu;
        AbT = abf8 + SU_BASE8 + (size_t)(tsu + wid) * TSZ8_SU;
        cbeg = (q * NCH_SU) >> 3;
        cend = ((q + 1) * NCH_SU) >> 3;
    }

    const int l15 = lane & 15, kq = lane >> 4;
    const unsigned char* Apl = AbT + (size_t)lane * 16;
    const unsigned char* Bpl = Yf2 + (size_t)lane * 16;

    f32x4 acc0 = {0.f,0.f,0.f,0.f}, acc1 = acc0;

    longx2 fa, fc;
    longx2 b0, b1, d0, d1;

#define LDA2(F, ch) do { F = *(const longx2*)(Apl + (size_t)(ch) * 1024); } while (0)
#define LDB2(B0,B1,ch) do { \
    const unsigned char* bb = Bpl + (size_t)(ch) * 2048; \
    B0 = *(const longx2*)(bb); \
    B1 = *(const longx2*)(bb + 1024); } while (0)
#define CMP4(F,B0,B1) do { \
    acc0 = MFMA8(F[0], B0[0], acc0, 0, 0, 0); \
    acc1 = MFMA8(F[0], B1[0], acc1, 0, 0, 0); \
    acc0 = MFMA8(F[1], B0[1], acc0, 0, 0, 0); \
    acc1 = MFMA8(F[1], B1[1], acc1, 0, 0, 0); } while (0)

    if (cbeg < cend) {
        LDA2(fa, cbeg);
        LDB2(b0, b1, cbeg);
        int ch = cbeg;
        while (ch + 2 <= cend) {
            LDA2(fc, ch + 1);
            LDB2(d0, d1, ch + 1);
            CMP4(fa, b0, b1);
            if (ch + 2 < cend) {
                LDA2(fa, ch + 2);
                LDB2(b0, b1, ch + 2);
            }
            CMP4(fc, d0, d1);
            ch += 2;
        }
        if (ch < cend) {
            CMP4(fa, b0, b1);
        }
    }
#undef LDA2
#undef LDB2
#undef CMP4

    float* Pp = p2 + ((size_t)q * TILES_TOT + tile0 + wid) * (16 * 32);
    #pragma unroll
    for (int j = 0; j < 4; ++j) {
        const int r = kq * 4 + j;
        Pp[r * 32 +      l15] = acc0[j];
        Pp[r * 32 + 16 + l15] = acc1[j];
    }
}

// ---------------- combine2: part[tile][c] = max_r (sum_q p2 + bc2 + init) ----------------
__global__ __launch_bounds__(256) void combine2_kernel(
    const float* __restrict__ p2, const float* __restrict__ bc2,
    const float* __restrict__ initb, float* __restrict__ part)
{
    const int idx = blockIdx.x * 256 + threadIdx.x;
    if (idx >= TILES_TOT * 32) return;
    const int gt = idx >> 5, c = idx & 31;
    int m0, M; const float* I;
    if (gt < 2 * T_SV) {
        int b = gt / T_SV;
        m0 = (gt - b * T_SV) * 16;
        M = NSV;
        I = initb + (size_t)ROWS_SU * 32 + (size_t)b * NSV * 32;
    } else {
        int t = gt - 2 * T_SV;
        int b = t / T_SU;
        m0 = (t - b * T_SU) * 16;
        M = NSU;
        I = initb + (size_t)b * NSU * 32;
    }
    const float* Q = p2 + (size_t)gt * 16 * 32 + c;
    const size_t QS = (size_t)TILES_TOT * 16 * 32;
    const float bb = bc2[c];
    float mx = NEG_INF;
    #pragma unroll
    for (int r = 0; r < 16; ++r) {
        const int m = m0 + r;
        if (m < M) {
            float s = bb + I[(size_t)m * 32 + c];
            #pragma unroll
            for (int qq = 0; qq < NH2; ++qq) s += Q[(size_t)qq * QS + r * 32];
            mx = fmaxf(mx, s);
        }
    }
    part[(size_t)gt * 32 + c] = mx;
}

// ---------------- head: pool-reduce + 4-layer MLP ----------------
__global__ __launch_bounds__(128) void head_kernel(
    const float* __restrict__ part,
    const float* __restrict__ Wfc2, const float* __restrict__ bfc2,
    const float* __restrict__ Wfc3, const float* __restrict__ bfc3,
    const float* __restrict__ Wfc4, const float* __restrict__ bfc4,
    const float* __restrict__ Wfc5, const float* __restrict__ bfc5,
    float* __restrict__ out)
{
    __shared__ float d[2][64];
    __shared__ float t1[2][32];
    __shared__ float t2[2][64];
    __shared__ float t3[2][32];
    const int tid = threadIdx.x;

    if (tid < 64) {
        const int b = tid >> 5, c = tid & 31;
        float m = NEG_INF;
        const float* ps = part + (size_t)(2 * T_SV + b * T_SU) * 32 + c;
        for (int i = 0; i < T_SU; ++i) m = fmaxf(m, ps[(size_t)i * 32]);
        d[b][c] = m;
        float m2 = NEG_INF;
        const float* pv = part + (size_t)b * T_SV * 32 + c;
        for (int i = 0; i < T_SV; ++i) m2 = fmaxf(m2, pv[(size_t)i * 32]);
        d[b][32 + c] = m2;
    }
    __syncthreads();
    if (tid < 64) {
        const int b = tid >> 5, c = tid & 31;
        float acc = bfc2[c];
        for (int f = 0; f < 64; ++f) acc += d[b][f] * Wfc2[f * 32 + c];
        t1[b][c] = fmaxf(acc, 0.f);
    }
    __syncthreads();
    {
        const int b = tid >> 6, c = tid & 63;
        float acc = bfc3[c];
        for (int f = 0; f < 32; ++f) acc += t1[b][f] * Wfc3[f * 64 + c];
        t2[b][c] = fmaxf(acc, 0.f);
    }
    __syncthreads();
    if (tid < 64) {
        const int b = tid >> 5, c = tid & 31;
        float acc = bfc4[c];
        for (int f = 0; f < 64; ++f) acc += t2[b][f] * Wfc4[f * 32 + c];
        t3[b][c] = fmaxf(acc, 0.f);
    }
    __syncthreads();
    if (tid < 2) {
        float acc = bfc5[0];
        for (int f = 0; f < 32; ++f) acc += t3[tid][f] * Wfc5[f];
        out[tid] = acc;
    }
}

extern "C" void kernel_launch(void* const* d_in, const int* in_sizes, int n_in,
                              void* d_out, int out_size, void* d_ws, size_t ws_size,
                              hipStream_t stream)
{
    const float* solute_adj   = (const float*)d_in[0];
    const float* solute_meth  = (const float*)d_in[1];
    const float* solvent_meth = (const float*)d_in[2];
    const float* solvent_adj  = (const float*)d_in[3];
    const float* W_fc1 = (const float*)d_in[4];
    const float* b_fc1 = (const float*)d_in[5];
    const float* W_c1  = (const float*)d_in[6];
    const float* b_c1  = (const float*)d_in[7];
    const float* W_c2  = (const float*)d_in[8];
    const float* b_c2  = (const float*)d_in[9];
    const float* W_fc2 = (const float*)d_in[10];
    const float* b_fc2 = (const float*)d_in[11];
    const float* W_fc3 = (const float*)d_in[12];
    const float* b_fc3 = (const float*)d_in[13];
    const float* W_fc4 = (const float*)d_in[14];
    const float* b_fc4 = (const float*)d_in[15];
    const float* W_fc5 = (const float*)d_in[16];
    const float* b_fc5 = (const float*)d_in[17];
    float* out = (float*)d_out;

    // workspace layout (bytes) — ~205 MB total (p1/p2 aliased: disjoint lifetimes)
    char* wsb = (char*)d_ws;
    size_t off = 0;
    unsigned short* y1tf = (unsigned short*)(wsb + off); off += 2850816;  // bf16 frag-major
    unsigned char*  y2f8 = (unsigned char*)(wsb + off);  off += 712704;   // fp8 frag-major
    off = (off + 15) & ~(size_t)15;
    float* initb         = (float*)(wsb + off);          off += 2820096;
    unsigned char* abf8  = (unsigned char*)(wsb + off);
    off += SU_BASE8 + (size_t)2 * T_SU * TSZ8_SU;                         // ~170 MB
    off = (off + 15) & ~(size_t)15;
    float* p1            = (float*)(wsb + off);
    float* p2            = p1;   // aliased: p1 dead after combine1
    off += (size_t)NH1 * PADROWS * 64 * 4;                                // 28.3 MB
    float* part          = (float*)(wsb + off);          off += (size_t)TILES_TOT * 32 * 4;

    pre_kernel<<<dim3((ROWS_ALL + 255) / 256), dim3(256), 0, stream>>>(
        solute_meth, solvent_meth, W_c1, W_fc1, b_fc1, y1tf, initb);

    conv1p_kernel<<<dim3(NBX_TOT, NH1), dim3(256), 0, stream>>>(
        solute_adj, solvent_adj, y1tf, abf8, p1);

    combine1_kernel<<<dim3(PADROWS / 64), dim3(256), 0, stream>>>(p1, b_c1, W_c2, y2f8);

    conv2p_kernel<<<dim3(NBX_TOT, NH2), dim3(256), 0, stream>>>(abf8, y2f8, p2);

    combine2_kernel<<<dim3((TILES_TOT * 32 + 255) / 256), dim3(256), 0, stream>>>(
        p2, b_c2, initb, part);

    head_kernel<<<dim3(1), dim3(128), 0, stream>>>(
        part, W_fc2, b_fc2, W_fc3, b_fc3, W_fc4, b_fc4, W_fc5, b_fc5, out);
}

// Round 15
// 440.827 us; speedup vs baseline: 1.3652x; 1.0704x over previous
//
#include <hip/hip_runtime.h>

#define B_      2
#define NSU     2076
#define NSV     8940
#define ROWS_SU (B_ * NSU)            // 4152
#define ROWS_ALL (B_ * (NSU + NSV))   // 22032
#define NB64_SV 140
#define NB64_SU 33
#define NBX_TOT (2 * NB64_SV + 2 * NB64_SU)   // 346
#define NH2     8                     // conv2 K-split
#define NCH_SV  140                   // k64 chunks per sv entity (conv2 reads)
#define NCH_SU  33                    // written chunks per su entity
#define TK_SV   140                   // conv1 k64 count (sv)
#define TK_SU   33                    // conv1 k64 count (su; k64 33 is all-pad, skipped)
#define T_SV    560                   // 16-row tiles per solvent batch
#define T_SU    132
#define TILES_TOT (2 * T_SV + 2 * T_SU)   // 1384
#define PADROWS (TILES_TOT * 16)          // 22144
#define TSZ8_SV ((size_t)140 * 1024)      // fp8 adjacency bytes per sv tile
#define TSZ8_SU ((size_t)34 * 1024)
#define SU_BASE8 ((size_t)2 * T_SV * TSZ8_SV)
#define PRE_BLKS ((ROWS_ALL + 255) / 256) // 87
#define NEG_INF (-3.402823466e38f)

// frag-major layouts (y1 bf16 shorts; y2 fp8 bytes)
#define Y1F_SV(b) ((size_t)(b) * 140 * 4096)
#define Y1F_SU(b) ((size_t)2 * 140 * 4096 + (size_t)(b) * 34 * 4096)
#define Y2F8_SV(b) ((size_t)(b) * 140 * 2048)
#define Y2F8_SU(b) ((size_t)2 * 140 * 2048 + (size_t)(b) * 34 * 2048)

typedef __attribute__((ext_vector_type(8))) short bf16x8;
typedef __attribute__((ext_vector_type(4))) float f32x4;
typedef __attribute__((ext_vector_type(2))) long longx2;

#define MFMA16 __builtin_amdgcn_mfma_f32_16x16x32_bf16
#define MFMA8  __builtin_amdgcn_mfma_f32_16x16x32_fp8_fp8

__device__ __forceinline__ unsigned short f2bf(float x) {
    unsigned int u = __float_as_uint(x);
    u += 0x7FFFu + ((u >> 16) & 1u);
    return (unsigned short)(u >> 16);
}
__device__ __forceinline__ unsigned int pkbf(float lo, float hi) {
    unsigned int r;
    asm("v_cvt_pk_bf16_f32 %0, %1, %2" : "=v"(r) : "v"(lo), "v"(hi));
    return r;
}
__device__ __forceinline__ int pk8lo(float lo, float hi, int old) {
    return __builtin_amdgcn_cvt_pk_fp8_f32(lo, hi, old, false);
}
__device__ __forceinline__ int pk8hi(float lo, float hi, int old) {
    return __builtin_amdgcn_cvt_pk_fp8_f32(lo, hi, old, true);
}
__device__ __forceinline__ float bf2f(short s) {
    return __uint_as_float(((unsigned int)(unsigned short)s) << 16);
}

// ---------------- pre: y1tf frag-major bf16 ; init ; wc2t ----------------
__global__ __launch_bounds__(256) void pre_kernel(
    const float* __restrict__ xsu, const float* __restrict__ xsv,
    const float* __restrict__ Wc1, const float* __restrict__ Wfc1,
    const float* __restrict__ bfc1, const float* __restrict__ Wc2g,
    unsigned short* __restrict__ y1tf, float* __restrict__ initb,
    unsigned short* __restrict__ wc2t)
{
    const int tid = threadIdx.x;
    if (blockIdx.x == PRE_BLKS) {     // wc2t[c*64+f] = bf16(Wc2[f][c])
        for (int idx = tid; idx < 2048; idx += 256) {
            const int c = idx >> 6, f = idx & 63;
            wc2t[idx] = f2bf(Wc2g[f * 32 + c]);
        }
        return;
    }

    __shared__ float sWc1[64 * 64];
    __shared__ float sWfc1[64 * 32];
    __shared__ float sb[32];
    for (int i = tid; i < 64 * 64; i += 256) sWc1[i] = Wc1[i];
    for (int i = tid; i < 64 * 32; i += 256) sWfc1[i] = Wfc1[i];
    if (tid < 32) sb[tid] = bfc1[tid];
    __syncthreads();

    const int rid = blockIdx.x * 256 + tid;
    if (rid >= ROWS_ALL) return;

    const float* xrow; unsigned short* yb; int m;
    if (rid < ROWS_SU) {
        int b = rid / NSU; m = rid - b * NSU;
        xrow = xsu + (size_t)rid * 64;
        yb = y1tf + Y1F_SU(b);
    } else {
        int r2 = rid - ROWS_SU;
        int b = r2 / NSV; m = r2 - b * NSV;
        xrow = xsv + (size_t)r2 * 64;
        yb = y1tf + Y1F_SV(b);
    }

    float xr[64];
    #pragma unroll
    for (int f4 = 0; f4 < 16; ++f4) {
        float4 v = ((const float4*)xrow)[f4];
        xr[f4 * 4 + 0] = v.x; xr[f4 * 4 + 1] = v.y;
        xr[f4 * 4 + 2] = v.z; xr[f4 * 4 + 3] = v.w;
    }
    {
        const int chunk = m >> 6, half = (m >> 5) & 1, kqq = (m >> 3) & 3, e = m & 7;
        unsigned short* yw = yb + (size_t)chunk * 4096 + half * 512 + e;
        for (int c = 0; c < 64; ++c) {
            float acc = 0.f;
            #pragma unroll
            for (int f = 0; f < 64; ++f) acc += xr[f] * sWc1[f * 64 + c];
            yw[(c >> 4) * 1024 + ((c & 15) + 16 * kqq) * 8] = f2bf(acc);
        }
    }
    float* ini = initb + (size_t)rid * 32;
    for (int c = 0; c < 32; ++c) {
        float acc = sb[c];
        #pragma unroll
        for (int f = 0; f < 64; ++f) acc += xr[f] * sWfc1[f * 32 + c];
        ini[c] = acc;
    }
}

// ---------------- conv1f: dense-staged conv1 + fp8 adj writeback + fused mid ------------
// Block = one 16-row tile, full K. Per 256-col chunk: each wave reads its 4 rows as
// single dense 1KB instructions -> cvt bf16 -> XOR-swizzled LDS -> barrier -> MFMA
// (wave = col-group, B dense frag-major) + per-wave dense fp8 frag writeback -> barrier.
// Epilogue fuses relu+bias+mid GEMM -> y2f8 frag-major fp8.
__global__ __launch_bounds__(256) void conv1f_kernel(
    const float* __restrict__ adj_su, const float* __restrict__ adj_sv,
    const unsigned short* __restrict__ y1tf,
    const float* __restrict__ bc1, const unsigned short* __restrict__ wc2t,
    unsigned char* __restrict__ abf8,
    unsigned char* __restrict__ y2f8)
{
    __shared__ unsigned short AL[4096];   // 4 k64 x 1024 shorts (8KB)
    __shared__ unsigned short HL[1024];   // 16x64 h bf16 (2KB)

    const int t = blockIdx.x;
    const int tid = threadIdx.x, lane = tid & 63, w = tid >> 6;
    const int l15 = lane & 15, kq = lane >> 4;

    int M, row0, TK;
    const float* A; const unsigned short* Yf;
    unsigned char* AbT; unsigned char* Y2b;
    if (t < 2 * T_SV) {
        int b = t / T_SV, rt = t - b * T_SV;
        M = NSV; TK = TK_SV;
        A = adj_sv + (size_t)b * NSV * NSV;
        Yf = y1tf + Y1F_SV(b);
        AbT = abf8 + (size_t)t * TSZ8_SV;
        Y2b = y2f8 + Y2F8_SV(b);
        row0 = rt * 16;
    } else {
        int u = t - 2 * T_SV;
        int b = u / T_SU, rt = u - b * T_SU;
        M = NSU; TK = TK_SU;
        A = adj_su + (size_t)b * NSU * NSU;
        Yf = y1tf + Y1F_SU(b);
        AbT = abf8 + SU_BASE8 + (size_t)u * TSZ8_SU;
        Y2b = y2f8 + Y2F8_SU(b);
        row0 = rt * 16;
    }

    const float* Ar[4];
    #pragma unroll
    for (int rr = 0; rr < 4; ++rr) {
        int r = row0 + w * 4 + rr;
        if (r >= M) r = M - 1;
        Ar[rr] = A + (size_t)r * M;
    }

    const int c4 = lane * 4;          // col within 256-col chunk
    const int k64i = c4 >> 6;
    const int c63 = c4 & 63;
    const int rxor = (l15 & 7) << 3;  // read-side swizzle

    f32x4 acc = {0.f, 0.f, 0.f, 0.f};

    for (int ch = 0; ch < TK; ch += 4) {
        const int cb = ch * 64;
        const int nk = (TK - ch < 4) ? (TK - ch) : 4;
        // ---- stage: 4 dense 1KB row reads per wave ----
        #pragma unroll
        for (int rr = 0; rr < 4; ++rr) {
            const int r = w * 4 + rr;
            const int col = cb + c4;
            float4 v = make_float4(0.f, 0.f, 0.f, 0.f);
            if (col < M) v = *(const float4*)(Ar[rr] + col);   // M%4==0
            const unsigned int u0 = pkbf(v.x, v.y);
            const unsigned int u1 = pkbf(v.z, v.w);
            const int sa = k64i * 1024 + r * 64 + (c63 ^ ((r & 7) << 3));
            *(uint2*)(&AL[sa]) = make_uint2(u0, u1);
        }
        __syncthreads();
        // ---- MFMA: wave w = col-group w ----
        #pragma unroll
        for (int j = 0; j < 4; ++j) {
            if (j < nk) {
                const bf16x8 af0 = *(const bf16x8*)(&AL[j * 1024 + l15 * 64 + ((kq * 8) ^ rxor)]);
                const bf16x8 af1 = *(const bf16x8*)(&AL[j * 1024 + l15 * 64 + ((32 + kq * 8) ^ rxor)]);
                const unsigned short* bb = Yf + (size_t)(ch + j) * 4096 + w * 1024 + lane * 8;
                const bf16x8 b0 = *(const bf16x8*)(bb);
                const bf16x8 b1 = *(const bf16x8*)(bb + 512);
                acc = MFMA16(af0, b0, acc, 0, 0, 0);
                acc = MFMA16(af1, b1, acc, 0, 0, 0);
            }
        }
        // ---- fp8 adjacency writeback: wave w writes k64 ch+w (dense 1KB per wave) ----
        if (w < nk) {
            const bf16x8 h0 = *(const bf16x8*)(&AL[w * 1024 + l15 * 64 + ((kq * 8) ^ rxor)]);
            const bf16x8 h1 = *(const bf16x8*)(&AL[w * 1024 + l15 * 64 + ((32 + kq * 8) ^ rxor)]);
            int q0 = pk8lo(bf2f(h0[0]), bf2f(h0[1]), 0); q0 = pk8hi(bf2f(h0[2]), bf2f(h0[3]), q0);
            int q1 = pk8lo(bf2f(h0[4]), bf2f(h0[5]), 0); q1 = pk8hi(bf2f(h0[6]), bf2f(h0[7]), q1);
            int q2 = pk8lo(bf2f(h1[0]), bf2f(h1[1]), 0); q2 = pk8hi(bf2f(h1[2]), bf2f(h1[3]), q2);
            int q3 = pk8lo(bf2f(h1[4]), bf2f(h1[5]), 0); q3 = pk8hi(bf2f(h1[6]), bf2f(h1[7]), q3);
            *(int4*)(AbT + (size_t)(ch + w) * 1024 + lane * 16) = make_int4(q0, q1, q2, q3);
        }
        __syncthreads();
    }

    // ---- fused mid: h = relu(acc + bc1) -> HL; y2 = h @ Wc2 -> y2f8 ----
    {
        const float bcv = bc1[w * 16 + l15];
        #pragma unroll
        for (int j = 0; j < 4; ++j) {
            const int r = kq * 4 + j;
            const int c = w * 16 + l15;
            HL[r * 64 + (c ^ ((r & 7) << 3))] = f2bf(fmaxf(acc[j] + bcv, 0.f));
        }
    }
    __syncthreads();
    if (w < 2) {
        const bf16x8 hf0 = *(const bf16x8*)(&HL[l15 * 64 + ((kq * 8) ^ rxor)]);
        const bf16x8 hf1 = *(const bf16x8*)(&HL[l15 * 64 + ((32 + kq * 8) ^ rxor)]);
        const unsigned short* wp = wc2t + (size_t)(w * 16 + l15) * 64 + kq * 8;
        const bf16x8 w0 = *(const bf16x8*)(wp);
        const bf16x8 w1 = *(const bf16x8*)(wp + 32);
        f32x4 m = {0.f, 0.f, 0.f, 0.f};
        m = MFMA16(hf0, w0, m, 0, 0, 0);
        m = MFMA16(hf1, w1, m, 0, 0, 0);
        const int mrow = row0 + kq * 4;           // 4 consecutive m-rows -> 4 packed bytes
        const int chm = mrow >> 6, r6 = mrow & 63;
        const int halfm = r6 >> 5, kqqm = (r6 >> 3) & 3, e0 = r6 & 7;
        const int c = w * 16 + l15;
        int pk = pk8lo(m[0], m[1], 0); pk = pk8hi(m[2], m[3], pk);
        *(int*)(Y2b + (size_t)chm * 2048 + (c >> 4) * 1024
                + (kqqm * 16 + (c & 15)) * 16 + halfm * 8 + e0) = pk;
    }
}

// ---------------- conv2 partial: FP8 MFMA, both operands dense frag-major ---------------
__global__ __launch_bounds__(256) void conv2p_kernel(
    const unsigned char* __restrict__ abf8,
    const unsigned char* __restrict__ y2f8,
    float* __restrict__ p2)
{
    const int bid = (NBX_TOT - 1) - blockIdx.x;
    const int q = blockIdx.y;
    const int tid = threadIdx.x, lane = tid & 63, wid = tid >> 6;
    int tile0, cbeg, cend;
    const unsigned char* Yf2; const unsigned char* AbT;
    if (bid < 2 * NB64_SV) {
        int b = bid / NB64_SV, rb = bid - b * NB64_SV;
        Yf2 = y2f8 + Y2F8_SV(b);
        tile0 = b * T_SV + rb * 4;
        AbT = abf8 + (size_t)(tile0 + wid) * TSZ8_SV;
        cbeg = (q * NCH_SV) >> 3;
        cend = ((q + 1) * NCH_SV) >> 3;
    } else {
        int t = bid - 2 * NB64_SV;
        int b = t / NB64_SU, rb = t - b * NB64_SU;
        Yf2 = y2f8 + Y2F8_SU(b);
        int tsu = b * T_SU + rb * 4;
        tile0 = 2 * T_SV + tsu;
        AbT = abf8 + SU_BASE8 + (size_t)(tsu + wid) * TSZ8_SU;
        cbeg = (q * NCH_SU) >> 3;
        cend = ((q + 1) * NCH_SU) >> 3;
    }

    const int l15 = lane & 15, kq = lane >> 4;
    const unsigned char* Apl = AbT + (size_t)lane * 16;
    const unsigned char* Bpl = Yf2 + (size_t)lane * 16;

    f32x4 acc0 = {0.f,0.f,0.f,0.f}, acc1 = acc0;

    longx2 fa, fc;
    longx2 b0, b1, d0, d1;

#define LDA2(F, ch) do { F = *(const longx2*)(Apl + (size_t)(ch) * 1024); } while (0)
#define LDB2(B0,B1,ch) do { \
    const unsigned char* bb = Bpl + (size_t)(ch) * 2048; \
    B0 = *(const longx2*)(bb); \
    B1 = *(const longx2*)(bb + 1024); } while (0)
#define CMP4(F,B0,B1) do { \
    acc0 = MFMA8(F[0], B0[0], acc0, 0, 0, 0); \
    acc1 = MFMA8(F[0], B1[0], acc1, 0, 0, 0); \
    acc0 = MFMA8(F[1], B0[1], acc0, 0, 0, 0); \
    acc1 = MFMA8(F[1], B1[1], acc1, 0, 0, 0); } while (0)

    if (cbeg < cend) {
        LDA2(fa, cbeg);
        LDB2(b0, b1, cbeg);
        int ch = cbeg;
        while (ch + 2 <= cend) {
            LDA2(fc, ch + 1);
            LDB2(d0, d1, ch + 1);
            CMP4(fa, b0, b1);
            if (ch + 2 < cend) {
                LDA2(fa, ch + 2);
                LDB2(b0, b1, ch + 2);
            }
            CMP4(fc, d0, d1);
            ch += 2;
        }
        if (ch < cend) {
            CMP4(fa, b0, b1);
        }
    }
#undef LDA2
#undef LDB2
#undef CMP4

    float* Pp = p2 + ((size_t)q * TILES_TOT + tile0 + wid) * (16 * 32);
    #pragma unroll
    for (int j = 0; j < 4; ++j) {
        const int r = kq * 4 + j;
        Pp[r * 32 +      l15] = acc0[j];
        Pp[r * 32 + 16 + l15] = acc1[j];
    }
}

// ---------------- combine2: part[tile][c] = max_r (sum_q p2 + bc2 + init) ----------------
__global__ __launch_bounds__(256) void combine2_kernel(
    const float* __restrict__ p2, const float* __restrict__ bc2,
    const float* __restrict__ initb, float* __restrict__ part)
{
    const int idx = blockIdx.x * 256 + threadIdx.x;
    if (idx >= TILES_TOT * 32) return;
    const int gt = idx >> 5, c = idx & 31;
    int m0, M; const float* I;
    if (gt < 2 * T_SV) {
        int b = gt / T_SV;
        m0 = (gt - b * T_SV) * 16;
        M = NSV;
        I = initb + (size_t)ROWS_SU * 32 + (size_t)b * NSV * 32;
    } else {
        int t = gt - 2 * T_SV;
        int b = t / T_SU;
        m0 = (t - b * T_SU) * 16;
        M = NSU;
        I = initb + (size_t)b * NSU * 32;
    }
    const float* Q = p2 + (size_t)gt * 16 * 32 + c;
    const size_t QS = (size_t)TILES_TOT * 16 * 32;
    const float bb = bc2[c];
    float mx = NEG_INF;
    #pragma unroll
    for (int r = 0; r < 16; ++r) {
        const int m = m0 + r;
        if (m < M) {
            float s = bb + I[(size_t)m * 32 + c];
            #pragma unroll
            for (int qq = 0; qq < NH2; ++qq) s += Q[(size_t)qq * QS + r * 32];
            mx = fmaxf(mx, s);
        }
    }
    part[(size_t)gt * 32 + c] = mx;
}

// ---------------- head: pool-reduce + 4-layer MLP ----------------
__global__ __launch_bounds__(128) void head_kernel(
    const float* __restrict__ part,
    const float* __restrict__ Wfc2, const float* __restrict__ bfc2,
    const float* __restrict__ Wfc3, const float* __restrict__ bfc3,
    const float* __restrict__ Wfc4, const float* __restrict__ bfc4,
    const float* __restrict__ Wfc5, const float* __restrict__ bfc5,
    float* __restrict__ out)
{
    __shared__ float d[2][64];
    __shared__ float t1[2][32];
    __shared__ float t2[2][64];
    __shared__ float t3[2][32];
    const int tid = threadIdx.x;

    if (tid < 64) {
        const int b = tid >> 5, c = tid & 31;
        float m = NEG_INF;
        const float* ps = part + (size_t)(2 * T_SV + b * T_SU) * 32 + c;
        for (int i = 0; i < T_SU; ++i) m = fmaxf(m, ps[(size_t)i * 32]);
        d[b][c] = m;
        float m2 = NEG_INF;
        const float* pv = part + (size_t)b * T_SV * 32 + c;
        for (int i = 0; i < T_SV; ++i) m2 = fmaxf(m2, pv[(size_t)i * 32]);
        d[b][32 + c] = m2;
    }
    __syncthreads();
    if (tid < 64) {
        const int b = tid >> 5, c = tid & 31;
        float acc = bfc2[c];
        for (int f = 0; f < 64; ++f) acc += d[b][f] * Wfc2[f * 32 + c];
        t1[b][c] = fmaxf(acc, 0.f);
    }
    __syncthreads();
    {
        const int b = tid >> 6, c = tid & 63;
        float acc = bfc3[c];
        for (int f = 0; f < 32; ++f) acc += t1[b][f] * Wfc3[f * 64 + c];
        t2[b][c] = fmaxf(acc, 0.f);
    }
    __syncthreads();
    if (tid < 64) {
        const int b = tid >> 5, c = tid & 31;
        float acc = bfc4[c];
        for (int f = 0; f < 64; ++f) acc += t2[b][f] * Wfc4[f * 32 + c];
        t3[b][c] = fmaxf(acc, 0.f);
    }
    __syncthreads();
    if (tid < 2) {
        float acc = bfc5[0];
        for (int f = 0; f < 32; ++f) acc += t3[tid][f] * Wfc5[f];
        out[tid] = acc;
    }
}

extern "C" void kernel_launch(void* const* d_in, const int* in_sizes, int n_in,
                              void* d_out, int out_size, void* d_ws, size_t ws_size,
                              hipStream_t stream)
{
    const float* solute_adj   = (const float*)d_in[0];
    const float* solute_meth  = (const float*)d_in[1];
    const float* solvent_meth = (const float*)d_in[2];
    const float* solvent_adj  = (const float*)d_in[3];
    const float* W_fc1 = (const float*)d_in[4];
    const float* b_fc1 = (const float*)d_in[5];
    const float* W_c1  = (const float*)d_in[6];
    const float* b_c1  = (const float*)d_in[7];
    const float* W_c2  = (const float*)d_in[8];
    const float* b_c2  = (const float*)d_in[9];
    const float* W_fc2 = (const float*)d_in[10];
    const float* b_fc2 = (const float*)d_in[11];
    const float* W_fc3 = (const float*)d_in[12];
    const float* b_fc3 = (const float*)d_in[13];
    const float* W_fc4 = (const float*)d_in[14];
    const float* b_fc4 = (const float*)d_in[15];
    const float* W_fc5 = (const float*)d_in[16];
    const float* b_fc5 = (const float*)d_in[17];
    float* out = (float*)d_out;

    // workspace layout (bytes) — ~200 MB
    char* wsb = (char*)d_ws;
    size_t off = 0;
    unsigned short* y1tf = (unsigned short*)(wsb + off); off += 2850816;
    unsigned char*  y2f8 = (unsigned char*)(wsb + off);  off += 712704;
    unsigned short* wc2t = (unsigned short*)(wsb + off); off += 4096;
    float* initb         = (float*)(wsb + off);          off += 2820096;
    unsigned char* abf8  = (unsigned char*)(wsb + off);
    off += SU_BASE8 + (size_t)2 * T_SU * TSZ8_SU;                         // ~170 MB
    off = (off + 15) & ~(size_t)15;
    float* p2            = (float*)(wsb + off);
    off += (size_t)NH2 * PADROWS * 32 * 4;                                // 22.7 MB
    float* part          = (float*)(wsb + off);          off += (size_t)TILES_TOT * 32 * 4;

    pre_kernel<<<dim3(PRE_BLKS + 1), dim3(256), 0, stream>>>(
        solute_meth, solvent_meth, W_c1, W_fc1, b_fc1, W_c2, y1tf, initb, wc2t);

    conv1f_kernel<<<dim3(TILES_TOT), dim3(256), 0, stream>>>(
        solute_adj, solvent_adj, y1tf, b_c1, wc2t, abf8, y2f8);

    conv2p_kernel<<<dim3(NBX_TOT, NH2), dim3(256), 0, stream>>>(abf8, y2f8, p2);

    combine2_kernel<<<dim3((TILES_TOT * 32 + 255) / 256), dim3(256), 0, stream>>>(
        p2, b_c2, initb, part);

    head_kernel<<<dim3(1), dim3(128), 0, stream>>>(
        part, W_fc2, b_fc2, W_fc3, b_fc3, W_fc4, b_fc4, W_fc5, b_fc5, out);
}

// Round 16
// 422.617 us; speedup vs baseline: 1.4241x; 1.0431x over previous
//
#include <hip/hip_runtime.h>

#define B_      2
#define NSU     2076
#define NSV     8940
#define ROWS_SU (B_ * NSU)            // 4152
#define ROWS_ALL (B_ * (NSU + NSV))   // 22032
#define NB64_SV 140
#define NB64_SU 33
#define NBX_TOT (2 * NB64_SV + 2 * NB64_SU)   // 346
#define NH2     8                     // conv2 K-split
#define NCH_SV  140                   // k64 chunks per sv entity (conv2 reads)
#define NCH_SU  33                    // written chunks per su entity
#define TK_SV   140                   // conv1 k64 count (sv)
#define TK_SU   33                    // conv1 k64 count (su)
#define T_SV    560                   // 16-row tiles per solvent batch
#define T_SU    132
#define TILES_TOT (2 * T_SV + 2 * T_SU)   // 1384
#define PADROWS (TILES_TOT * 16)          // 22144
#define TSZ8_SV ((size_t)140 * 1024)      // fp8 adjacency bytes per sv tile
#define TSZ8_SU ((size_t)34 * 1024)
#define SU_BASE8 ((size_t)2 * T_SV * TSZ8_SV)
#define PRE_BLKS ((ROWS_ALL + 255) / 256) // 87
#define NEG_INF (-3.402823466e38f)

// frag-major layouts (y1 bf16 shorts; y2 fp8 bytes)
#define Y1F_SV(b) ((size_t)(b) * 140 * 4096)
#define Y1F_SU(b) ((size_t)2 * 140 * 4096 + (size_t)(b) * 34 * 4096)
#define Y2F8_SV(b) ((size_t)(b) * 140 * 2048)
#define Y2F8_SU(b) ((size_t)2 * 140 * 2048 + (size_t)(b) * 34 * 2048)

typedef __attribute__((ext_vector_type(8))) short bf16x8;
typedef __attribute__((ext_vector_type(4))) float f32x4;
typedef __attribute__((ext_vector_type(2))) long longx2;

#define MFMA16 __builtin_amdgcn_mfma_f32_16x16x32_bf16
#define MFMA8  __builtin_amdgcn_mfma_f32_16x16x32_fp8_fp8

__device__ __forceinline__ unsigned short f2bf(float x) {
    unsigned int u = __float_as_uint(x);
    u += 0x7FFFu + ((u >> 16) & 1u);
    return (unsigned short)(u >> 16);
}
__device__ __forceinline__ unsigned int pkbf(float lo, float hi) {
    unsigned int r;
    asm("v_cvt_pk_bf16_f32 %0, %1, %2" : "=v"(r) : "v"(lo), "v"(hi));
    return r;
}
__device__ __forceinline__ int pk8lo(float lo, float hi, int old) {
    return __builtin_amdgcn_cvt_pk_fp8_f32(lo, hi, old, false);
}
__device__ __forceinline__ int pk8hi(float lo, float hi, int old) {
    return __builtin_amdgcn_cvt_pk_fp8_f32(lo, hi, old, true);
}
__device__ __forceinline__ float bf2f(short s) {
    return __uint_as_float(((unsigned int)(unsigned short)s) << 16);
}

// ---------------- pre: y1tf frag-major bf16 ; init ; wc2t ----------------
__global__ __launch_bounds__(256) void pre_kernel(
    const float* __restrict__ xsu, const float* __restrict__ xsv,
    const float* __restrict__ Wc1, const float* __restrict__ Wfc1,
    const float* __restrict__ bfc1, const float* __restrict__ Wc2g,
    unsigned short* __restrict__ y1tf, float* __restrict__ initb,
    unsigned short* __restrict__ wc2t)
{
    const int tid = threadIdx.x;
    if (blockIdx.x == PRE_BLKS) {     // wc2t[c*64+f] = bf16(Wc2[f][c])
        for (int idx = tid; idx < 2048; idx += 256) {
            const int c = idx >> 6, f = idx & 63;
            wc2t[idx] = f2bf(Wc2g[f * 32 + c]);
        }
        return;
    }

    __shared__ float sWc1[64 * 64];
    __shared__ float sWfc1[64 * 32];
    __shared__ float sb[32];
    for (int i = tid; i < 64 * 64; i += 256) sWc1[i] = Wc1[i];
    for (int i = tid; i < 64 * 32; i += 256) sWfc1[i] = Wfc1[i];
    if (tid < 32) sb[tid] = bfc1[tid];
    __syncthreads();

    const int rid = blockIdx.x * 256 + tid;
    if (rid >= ROWS_ALL) return;

    const float* xrow; unsigned short* yb; int m;
    if (rid < ROWS_SU) {
        int b = rid / NSU; m = rid - b * NSU;
        xrow = xsu + (size_t)rid * 64;
        yb = y1tf + Y1F_SU(b);
    } else {
        int r2 = rid - ROWS_SU;
        int b = r2 / NSV; m = r2 - b * NSV;
        xrow = xsv + (size_t)r2 * 64;
        yb = y1tf + Y1F_SV(b);
    }

    float xr[64];
    #pragma unroll
    for (int f4 = 0; f4 < 16; ++f4) {
        float4 v = ((const float4*)xrow)[f4];
        xr[f4 * 4 + 0] = v.x; xr[f4 * 4 + 1] = v.y;
        xr[f4 * 4 + 2] = v.z; xr[f4 * 4 + 3] = v.w;
    }
    {
        const int chunk = m >> 6, half = (m >> 5) & 1, kqq = (m >> 3) & 3, e = m & 7;
        unsigned short* yw = yb + (size_t)chunk * 4096 + half * 512 + e;
        for (int c = 0; c < 64; ++c) {
            float acc = 0.f;
            #pragma unroll
            for (int f = 0; f < 64; ++f) acc += xr[f] * sWc1[f * 64 + c];
            yw[(c >> 4) * 1024 + ((c & 15) + 16 * kqq) * 8] = f2bf(acc);
        }
    }
    float* ini = initb + (size_t)rid * 32;
    for (int c = 0; c < 32; ++c) {
        float acc = sb[c];
        #pragma unroll
        for (int f = 0; f < 64; ++f) acc += xr[f] * sWfc1[f * 32 + c];
        ini[c] = acc;
    }
}

// ---------------- conv1f: double-buffered dense-staged conv1 + fp8 writeback + mid ------
// Block = one 16-row tile, full K. Register->LDS double buffer: next group's dense 1KB
// row loads issue right AFTER the barrier and retire during the MFMA/writeback phase.
// One barrier per 4-chunk group (iter-g reads of AL[g&1] and iter-(g+2) writes are
// separated by iter-(g+1)'s barrier).
__global__ __launch_bounds__(256) void conv1f_kernel(
    const float* __restrict__ adj_su, const float* __restrict__ adj_sv,
    const unsigned short* __restrict__ y1tf,
    const float* __restrict__ bc1, const unsigned short* __restrict__ wc2t,
    unsigned char* __restrict__ abf8,
    unsigned char* __restrict__ y2f8)
{
    __shared__ unsigned short AL[2][4096];   // 2 x (4 k64 x 1024 shorts) = 16KB
    __shared__ unsigned short HL[1024];      // 16x64 h bf16 (2KB)

    const int t = blockIdx.x;
    const int tid = threadIdx.x, lane = tid & 63, w = tid >> 6;
    const int l15 = lane & 15, kq = lane >> 4;

    int M, row0, TK;
    const float* A; const unsigned short* Yf;
    unsigned char* AbT; unsigned char* Y2b;
    if (t < 2 * T_SV) {
        int b = t / T_SV, rt = t - b * T_SV;
        M = NSV; TK = TK_SV;
        A = adj_sv + (size_t)b * NSV * NSV;
        Yf = y1tf + Y1F_SV(b);
        AbT = abf8 + (size_t)t * TSZ8_SV;
        Y2b = y2f8 + Y2F8_SV(b);
        row0 = rt * 16;
    } else {
        int u = t - 2 * T_SV;
        int b = u / T_SU, rt = u - b * T_SU;
        M = NSU; TK = TK_SU;
        A = adj_su + (size_t)b * NSU * NSU;
        Yf = y1tf + Y1F_SU(b);
        AbT = abf8 + SU_BASE8 + (size_t)u * TSZ8_SU;
        Y2b = y2f8 + Y2F8_SU(b);
        row0 = rt * 16;
    }

    const float* Ar[4];
    #pragma unroll
    for (int rr = 0; rr < 4; ++rr) {
        int r = row0 + w * 4 + rr;
        if (r >= M) r = M - 1;
        Ar[rr] = A + (size_t)r * M;
    }

    const int c4 = lane * 4;          // col within 256-col group
    const int k64i = c4 >> 6;
    const int c63 = c4 & 63;
    const int rxor = (l15 & 7) << 3;  // read-side swizzle

    f32x4 acc = {0.f, 0.f, 0.f, 0.f};

    float4 av[4];
    // prologue: load group 0 (cols 0..255)
    #pragma unroll
    for (int rr = 0; rr < 4; ++rr) {
        float4 v = make_float4(0.f, 0.f, 0.f, 0.f);
        if (c4 < M) v = *(const float4*)(Ar[rr] + c4);     // M%4==0
        av[rr] = v;
    }

    const int G = (TK + 3) >> 2;
    for (int g = 0; g < G; ++g) {
        const int ch = g * 4;
        const int nk = (TK - ch < 4) ? (TK - ch) : 4;
        unsigned short* buf = &AL[g & 1][0];
        // ---- store staged regs (cvt to bf16, XOR-swizzled) ----
        #pragma unroll
        for (int rr = 0; rr < 4; ++rr) {
            const int r = w * 4 + rr;
            const unsigned int u0 = pkbf(av[rr].x, av[rr].y);
            const unsigned int u1 = pkbf(av[rr].z, av[rr].w);
            const int sa = k64i * 1024 + r * 64 + (c63 ^ ((r & 7) << 3));
            *(uint2*)(&buf[sa]) = make_uint2(u0, u1);
        }
        __syncthreads();
        // ---- prefetch next group (loads retire during MFMA below) ----
        if (g + 1 < G) {
            const int cb2 = (g + 1) * 256;
            #pragma unroll
            for (int rr = 0; rr < 4; ++rr) {
                const int col = cb2 + c4;
                float4 v = make_float4(0.f, 0.f, 0.f, 0.f);
                if (col < M) v = *(const float4*)(Ar[rr] + col);
                av[rr] = v;
            }
        }
        // ---- MFMA: wave w = col-group w ----
        #pragma unroll
        for (int j = 0; j < 4; ++j) {
            if (j < nk) {
                const bf16x8 af0 = *(const bf16x8*)(&buf[j * 1024 + l15 * 64 + ((kq * 8) ^ rxor)]);
                const bf16x8 af1 = *(const bf16x8*)(&buf[j * 1024 + l15 * 64 + ((32 + kq * 8) ^ rxor)]);
                const unsigned short* bb = Yf + (size_t)(ch + j) * 4096 + w * 1024 + lane * 8;
                const bf16x8 b0 = *(const bf16x8*)(bb);
                const bf16x8 b1 = *(const bf16x8*)(bb + 512);
                acc = MFMA16(af0, b0, acc, 0, 0, 0);
                acc = MFMA16(af1, b1, acc, 0, 0, 0);
            }
        }
        // ---- fp8 adjacency writeback: wave w writes k64 ch+w (dense 1KB per wave) ----
        if (w < nk) {
            const bf16x8 h0 = *(const bf16x8*)(&buf[w * 1024 + l15 * 64 + ((kq * 8) ^ rxor)]);
            const bf16x8 h1 = *(const bf16x8*)(&buf[w * 1024 + l15 * 64 + ((32 + kq * 8) ^ rxor)]);
            int q0 = pk8lo(bf2f(h0[0]), bf2f(h0[1]), 0); q0 = pk8hi(bf2f(h0[2]), bf2f(h0[3]), q0);
            int q1 = pk8lo(bf2f(h0[4]), bf2f(h0[5]), 0); q1 = pk8hi(bf2f(h0[6]), bf2f(h0[7]), q1);
            int q2 = pk8lo(bf2f(h1[0]), bf2f(h1[1]), 0); q2 = pk8hi(bf2f(h1[2]), bf2f(h1[3]), q2);
            int q3 = pk8lo(bf2f(h1[4]), bf2f(h1[5]), 0); q3 = pk8hi(bf2f(h1[6]), bf2f(h1[7]), q3);
            *(int4*)(AbT + (size_t)(ch + w) * 1024 + lane * 16) = make_int4(q0, q1, q2, q3);
        }
    }

    __syncthreads();   // drain last group's cross-wave LDS reads before HL reuse phase
    // ---- fused mid: h = relu(acc + bc1) -> HL; y2 = h @ Wc2 -> y2f8 ----
    {
        const float bcv = bc1[w * 16 + l15];
        #pragma unroll
        for (int j = 0; j < 4; ++j) {
            const int r = kq * 4 + j;
            const int c = w * 16 + l15;
            HL[r * 64 + (c ^ ((r & 7) << 3))] = f2bf(fmaxf(acc[j] + bcv, 0.f));
        }
    }
    __syncthreads();
    if (w < 2) {
        const bf16x8 hf0 = *(const bf16x8*)(&HL[l15 * 64 + ((kq * 8) ^ rxor)]);
        const bf16x8 hf1 = *(const bf16x8*)(&HL[l15 * 64 + ((32 + kq * 8) ^ rxor)]);
        const unsigned short* wp = wc2t + (size_t)(w * 16 + l15) * 64 + kq * 8;
        const bf16x8 w0 = *(const bf16x8*)(wp);
        const bf16x8 w1 = *(const bf16x8*)(wp + 32);
        f32x4 m = {0.f, 0.f, 0.f, 0.f};
        m = MFMA16(hf0, w0, m, 0, 0, 0);
        m = MFMA16(hf1, w1, m, 0, 0, 0);
        const int mrow = row0 + kq * 4;
        const int chm = mrow >> 6, r6 = mrow & 63;
        const int halfm = r6 >> 5, kqqm = (r6 >> 3) & 3, e0 = r6 & 7;
        const int c = w * 16 + l15;
        int pk = pk8lo(m[0], m[1], 0); pk = pk8hi(m[2], m[3], pk);
        *(int*)(Y2b + (size_t)chm * 2048 + (c >> 4) * 1024
                + (kqqm * 16 + (c & 15)) * 16 + halfm * 8 + e0) = pk;
    }
}

// ---------------- conv2 partial: FP8 MFMA, both operands dense frag-major ---------------
__global__ __launch_bounds__(256) void conv2p_kernel(
    const unsigned char* __restrict__ abf8,
    const unsigned char* __restrict__ y2f8,
    float* __restrict__ p2)
{
    const int bid = (NBX_TOT - 1) - blockIdx.x;
    const int q = blockIdx.y;
    const int tid = threadIdx.x, lane = tid & 63, wid = tid >> 6;
    int tile0, cbeg, cend;
    const unsigned char* Yf2; const unsigned char* AbT;
    if (bid < 2 * NB64_SV) {
        int b = bid / NB64_SV, rb = bid - b * NB64_SV;
        Yf2 = y2f8 + Y2F8_SV(b);
        tile0 = b * T_SV + rb * 4;
        AbT = abf8 + (size_t)(tile0 + wid) * TSZ8_SV;
        cbeg = (q * NCH_SV) >> 3;
        cend = ((q + 1) * NCH_SV) >> 3;
    } else {
        int t = bid - 2 * NB64_SV;
        int b = t / NB64_SU, rb = t - b * NB64_SU;
        Yf2 = y2f8 + Y2F8_SU(b);
        int tsu = b * T_SU + rb * 4;
        tile0 = 2 * T_SV + tsu;
        AbT = abf8 + SU_BASE8 + (size_t)(tsu + wid) * TSZ8_SU;
        cbeg = (q * NCH_SU) >> 3;
        cend = ((q + 1) * NCH_SU) >> 3;
    }

    const int l15 = lane & 15, kq = lane >> 4;
    const unsigned char* Apl = AbT + (size_t)lane * 16;
    const unsigned char* Bpl = Yf2 + (size_t)lane * 16;

    f32x4 acc0 = {0.f,0.f,0.f,0.f}, acc1 = acc0;

    longx2 fa, fc;
    longx2 b0, b1, d0, d1;

#define LDA2(F, ch) do { F = *(const longx2*)(Apl + (size_t)(ch) * 1024); } while (0)
#define LDB2(B0,B1,ch) do { \
    const unsigned char* bb = Bpl + (size_t)(ch) * 2048; \
    B0 = *(const longx2*)(bb); \
    B1 = *(const longx2*)(bb + 1024); } while (0)
#define CMP4(F,B0,B1) do { \
    acc0 = MFMA8(F[0], B0[0], acc0, 0, 0, 0); \
    acc1 = MFMA8(F[0], B1[0], acc1, 0, 0, 0); \
    acc0 = MFMA8(F[1], B0[1], acc0, 0, 0, 0); \
    acc1 = MFMA8(F[1], B1[1], acc1, 0, 0, 0); } while (0)

    if (cbeg < cend) {
        LDA2(fa, cbeg);
        LDB2(b0, b1, cbeg);
        int ch = cbeg;
        while (ch + 2 <= cend) {
            LDA2(fc, ch + 1);
            LDB2(d0, d1, ch + 1);
            CMP4(fa, b0, b1);
            if (ch + 2 < cend) {
                LDA2(fa, ch + 2);
                LDB2(b0, b1, ch + 2);
            }
            CMP4(fc, d0, d1);
            ch += 2;
        }
        if (ch < cend) {
            CMP4(fa, b0, b1);
        }
    }
#undef LDA2
#undef LDB2
#undef CMP4

    float* Pp = p2 + ((size_t)q * TILES_TOT + tile0 + wid) * (16 * 32);
    #pragma unroll
    for (int j = 0; j < 4; ++j) {
        const int r = kq * 4 + j;
        Pp[r * 32 +      l15] = acc0[j];
        Pp[r * 32 + 16 + l15] = acc1[j];
    }
}

// ---------------- combine2: part[tile][c] = max_r (sum_q p2 + bc2 + init) ----------------
__global__ __launch_bounds__(256) void combine2_kernel(
    const float* __restrict__ p2, const float* __restrict__ bc2,
    const float* __restrict__ initb, float* __restrict__ part)
{
    const int idx = blockIdx.x * 256 + threadIdx.x;
    if (idx >= TILES_TOT * 32) return;
    const int gt = idx >> 5, c = idx & 31;
    int m0, M; const float* I;
    if (gt < 2 * T_SV) {
        int b = gt / T_SV;
        m0 = (gt - b * T_SV) * 16;
        M = NSV;
        I = initb + (size_t)ROWS_SU * 32 + (size_t)b * NSV * 32;
    } else {
        int t = gt - 2 * T_SV;
        int b = t / T_SU;
        m0 = (t - b * T_SU) * 16;
        M = NSU;
        I = initb + (size_t)b * NSU * 32;
    }
    const float* Q = p2 + (size_t)gt * 16 * 32 + c;
    const size_t QS = (size_t)TILES_TOT * 16 * 32;
    const float bb = bc2[c];
    float mx = NEG_INF;
    #pragma unroll
    for (int r = 0; r < 16; ++r) {
        const int m = m0 + r;
        if (m < M) {
            float s = bb + I[(size_t)m * 32 + c];
            #pragma unroll
            for (int qq = 0; qq < NH2; ++qq) s += Q[(size_t)qq * QS + r * 32];
            mx = fmaxf(mx, s);
        }
    }
    part[(size_t)gt * 32 + c] = mx;
}

// ---------------- head: pool-reduce + 4-layer MLP ----------------
__global__ __launch_bounds__(128) void head_kernel(
    const float* __restrict__ part,
    const float* __restrict__ Wfc2, const float* __restrict__ bfc2,
    const float* __restrict__ Wfc3, const float* __restrict__ bfc3,
    const float* __restrict__ Wfc4, const float* __restrict__ bfc4,
    const float* __restrict__ Wfc5, const float* __restrict__ bfc5,
    float* __restrict__ out)
{
    __shared__ float d[2][64];
    __shared__ float t1[2][32];
    __shared__ float t2[2][64];
    __shared__ float t3[2][32];
    const int tid = threadIdx.x;

    if (tid < 64) {
        const int b = tid >> 5, c = tid & 31;
        float m = NEG_INF;
        const float* ps = part + (size_t)(2 * T_SV + b * T_SU) * 32 + c;
        for (int i = 0; i < T_SU; ++i) m = fmaxf(m, ps[(size_t)i * 32]);
        d[b][c] = m;
        float m2 = NEG_INF;
        const float* pv = part + (size_t)b * T_SV * 32 + c;
        for (int i = 0; i < T_SV; ++i) m2 = fmaxf(m2, pv[(size_t)i * 32]);
        d[b][32 + c] = m2;
    }
    __syncthreads();
    if (tid < 64) {
        const int b = tid >> 5, c = tid & 31;
        float acc = bfc2[c];
        for (int f = 0; f < 64; ++f) acc += d[b][f] * Wfc2[f * 32 + c];
        t1[b][c] = fmaxf(acc, 0.f);
    }
    __syncthreads();
    {
        const int b = tid >> 6, c = tid & 63;
        float acc = bfc3[c];
        for (int f = 0; f < 32; ++f) acc += t1[b][f] * Wfc3[f * 64 + c];
        t2[b][c] = fmaxf(acc, 0.f);
    }
    __syncthreads();
    if (tid < 64) {
        const int b = tid >> 5, c = tid & 31;
        float acc = bfc4[c];
        for (int f = 0; f < 64; ++f) acc += t2[b][f] * Wfc4[f * 32 + c];
        t3[b][c] = fmaxf(acc, 0.f);
    }
    __syncthreads();
    if (tid < 2) {
        float acc = bfc5[0];
        for (int f = 0; f < 32; ++f) acc += t3[tid][f] * Wfc5[f];
        out[tid] = acc;
    }
}

extern "C" void kernel_launch(void* const* d_in, const int* in_sizes, int n_in,
                              void* d_out, int out_size, void* d_ws, size_t ws_size,
                              hipStream_t stream)
{
    const float* solute_adj   = (const float*)d_in[0];
    const float* solute_meth  = (const float*)d_in[1];
    const float* solvent_meth = (const float*)d_in[2];
    const float* solvent_adj  = (const float*)d_in[3];
    const float* W_fc1 = (const float*)d_in[4];
    const float* b_fc1 = (const float*)d_in[5];
    const float* W_c1  = (const float*)d_in[6];
    const float* b_c1  = (const float*)d_in[7];
    const float* W_c2  = (const float*)d_in[8];
    const float* b_c2  = (const float*)d_in[9];
    const float* W_fc2 = (const float*)d_in[10];
    const float* b_fc2 = (const float*)d_in[11];
    const float* W_fc3 = (const float*)d_in[12];
    const float* b_fc3 = (const float*)d_in[13];
    const float* W_fc4 = (const float*)d_in[14];
    const float* b_fc4 = (const float*)d_in[15];
    const float* W_fc5 = (const float*)d_in[16];
    const float* b_fc5 = (const float*)d_in[17];
    float* out = (float*)d_out;

    // workspace layout (bytes) — ~200 MB
    char* wsb = (char*)d_ws;
    size_t off = 0;
    unsigned short* y1tf = (unsigned short*)(wsb + off); off += 2850816;
    unsigned char*  y2f8 = (unsigned char*)(wsb + off);  off += 712704;
    unsigned short* wc2t = (unsigned short*)(wsb + off); off += 4096;
    float* initb         = (float*)(wsb + off);          off += 2820096;
    unsigned char* abf8  = (unsigned char*)(wsb + off);
    off += SU_BASE8 + (size_t)2 * T_SU * TSZ8_SU;                         // ~170 MB
    off = (off + 15) & ~(size_t)15;
    float* p2            = (float*)(wsb + off);
    off += (size_t)NH2 * PADROWS * 32 * 4;                                // 22.7 MB
    float* part          = (float*)(wsb + off);          off += (size_t)TILES_TOT * 32 * 4;

    pre_kernel<<<dim3(PRE_BLKS + 1), dim3(256), 0, stream>>>(
        solute_meth, solvent_meth, W_c1, W_fc1, b_fc1, W_c2, y1tf, initb, wc2t);

    conv1f_kernel<<<dim3(TILES_TOT), dim3(256), 0, stream>>>(
        solute_adj, solvent_adj, y1tf, b_c1, wc2t, abf8, y2f8);

    conv2p_kernel<<<dim3(NBX_TOT, NH2), dim3(256), 0, stream>>>(abf8, y2f8, p2);

    combine2_kernel<<<dim3((TILES_TOT * 32 + 255) / 256), dim3(256), 0, stream>>>(
        p2, b_c2, initb, part);

    head_kernel<<<dim3(1), dim3(128), 0, stream>>>(
        part, W_fc2, b_fc2, W_fc3, b_fc3, W_fc4, b_fc4, W_fc5, b_fc5, out);
}

// Round 17
// 413.962 us; speedup vs baseline: 1.4538x; 1.0209x over previous
//
#include <hip/hip_runtime.h>

#define B_      2
#define NSU     2076
#define NSV     8940
#define ROWS_SU (B_ * NSU)            // 4152
#define ROWS_ALL (B_ * (NSU + NSV))   // 22032
#define NB64_SV 140
#define NB64_SU 33
#define NBX_TOT (2 * NB64_SV + 2 * NB64_SU)   // 346
#define NH2     8
#define NCH_SV  140
#define NCH_SU  33
#define TK_SV   140
#define TK_SU   33
#define T_SV    560
#define T_SU    132
#define TILES_TOT (2 * T_SV + 2 * T_SU)   // 1384
#define PADROWS (TILES_TOT * 16)
#define TSZ8_SV ((size_t)140 * 1024)
#define TSZ8_SU ((size_t)34 * 1024)
#define SU_BASE8 ((size_t)2 * T_SV * TSZ8_SV)
#define PRE_BLKS ((ROWS_ALL + 255) / 256)
#define NEG_INF (-3.402823466e38f)

#define Y1F_SV(b) ((size_t)(b) * 140 * 4096)
#define Y1F_SU(b) ((size_t)2 * 140 * 4096 + (size_t)(b) * 34 * 4096)
#define Y2F8_SV(b) ((size_t)(b) * 140 * 2048)
#define Y2F8_SU(b) ((size_t)2 * 140 * 2048 + (size_t)(b) * 34 * 2048)

typedef __attribute__((ext_vector_type(8))) short bf16x8;
typedef __attribute__((ext_vector_type(4))) float f32x4;
typedef __attribute__((ext_vector_type(2))) long longx2;

#define MFMA16 __builtin_amdgcn_mfma_f32_16x16x32_bf16
#define MFMA8  __builtin_amdgcn_mfma_f32_16x16x32_fp8_fp8

__device__ __forceinline__ unsigned short f2bf(float x) {
    unsigned int u = __float_as_uint(x);
    u += 0x7FFFu + ((u >> 16) & 1u);
    return (unsigned short)(u >> 16);
}
__device__ __forceinline__ unsigned int pkbf(float lo, float hi) {
    unsigned int r;
    asm("v_cvt_pk_bf16_f32 %0, %1, %2" : "=v"(r) : "v"(lo), "v"(hi));
    return r;
}
__device__ __forceinline__ int pk8lo(float lo, float hi, int old) {
    return __builtin_amdgcn_cvt_pk_fp8_f32(lo, hi, old, false);
}
__device__ __forceinline__ int pk8hi(float lo, float hi, int old) {
    return __builtin_amdgcn_cvt_pk_fp8_f32(lo, hi, old, true);
}
__device__ __forceinline__ float bf2f(short s) {
    return __uint_as_float(((unsigned int)(unsigned short)s) << 16);
}

// ---------------- pre: y1tf frag-major bf16 ; init ; wc2t ----------------
__global__ __launch_bounds__(256) void pre_kernel(
    const float* __restrict__ xsu, const float* __restrict__ xsv,
    const float* __restrict__ Wc1, const float* __restrict__ Wfc1,
    const float* __restrict__ bfc1, const float* __restrict__ Wc2g,
    unsigned short* __restrict__ y1tf, float* __restrict__ initb,
    unsigned short* __restrict__ wc2t)
{
    const int tid = threadIdx.x;
    if (blockIdx.x == PRE_BLKS) {
        for (int idx = tid; idx < 2048; idx += 256) {
            const int c = idx >> 6, f = idx & 63;
            wc2t[idx] = f2bf(Wc2g[f * 32 + c]);
        }
        return;
    }

    __shared__ float sWc1[64 * 64];
    __shared__ float sWfc1[64 * 32];
    __shared__ float sb[32];
    for (int i = tid; i < 64 * 64; i += 256) sWc1[i] = Wc1[i];
    for (int i = tid; i < 64 * 32; i += 256) sWfc1[i] = Wfc1[i];
    if (tid < 32) sb[tid] = bfc1[tid];
    __syncthreads();

    const int rid = blockIdx.x * 256 + tid;
    if (rid >= ROWS_ALL) return;

    const float* xrow; unsigned short* yb; int m;
    if (rid < ROWS_SU) {
        int b = rid / NSU; m = rid - b * NSU;
        xrow = xsu + (size_t)rid * 64;
        yb = y1tf + Y1F_SU(b);
    } else {
        int r2 = rid - ROWS_SU;
        int b = r2 / NSV; m = r2 - b * NSV;
        xrow = xsv + (size_t)r2 * 64;
        yb = y1tf + Y1F_SV(b);
    }

    float xr[64];
    #pragma unroll
    for (int f4 = 0; f4 < 16; ++f4) {
        float4 v = ((const float4*)xrow)[f4];
        xr[f4 * 4 + 0] = v.x; xr[f4 * 4 + 1] = v.y;
        xr[f4 * 4 + 2] = v.z; xr[f4 * 4 + 3] = v.w;
    }
    {
        const int chunk = m >> 6, half = (m >> 5) & 1, kqq = (m >> 3) & 3, e = m & 7;
        unsigned short* yw = yb + (size_t)chunk * 4096 + half * 512 + e;
        for (int c = 0; c < 64; ++c) {
            float acc = 0.f;
            #pragma unroll
            for (int f = 0; f < 64; ++f) acc += xr[f] * sWc1[f * 64 + c];
            yw[(c >> 4) * 1024 + ((c & 15) + 16 * kqq) * 8] = f2bf(acc);
        }
    }
    float* ini = initb + (size_t)rid * 32;
    for (int c = 0; c < 32; ++c) {
        float acc = sb[c];
        #pragma unroll
        for (int f = 0; f < 64; ++f) acc += xr[f] * sWfc1[f * 32 + c];
        ini[c] = acc;
    }
}

// ---------------- conv1f: depth-2 reg prefetch + LDS dbuf + fp8 writeback + mid ---------
__global__ __launch_bounds__(256) void conv1f_kernel(
    const float* __restrict__ adj_su, const float* __restrict__ adj_sv,
    const unsigned short* __restrict__ y1tf,
    const float* __restrict__ bc1, const unsigned short* __restrict__ wc2t,
    unsigned char* __restrict__ abf8,
    unsigned char* __restrict__ y2f8)
{
    __shared__ unsigned short AL[2][4096];   // 16KB
    __shared__ unsigned short HL[1024];      // 2KB

    const int t = blockIdx.x;
    const int tid = threadIdx.x, lane = tid & 63, w = tid >> 6;
    const int l15 = lane & 15, kq = lane >> 4;

    int M, row0, TK;
    const float* A; const unsigned short* Yf;
    unsigned char* AbT; unsigned char* Y2b;
    if (t < 2 * T_SV) {
        int b = t / T_SV, rt = t - b * T_SV;
        M = NSV; TK = TK_SV;
        A = adj_sv + (size_t)b * NSV * NSV;
        Yf = y1tf + Y1F_SV(b);
        AbT = abf8 + (size_t)t * TSZ8_SV;
        Y2b = y2f8 + Y2F8_SV(b);
        row0 = rt * 16;
    } else {
        int u = t - 2 * T_SV;
        int b = u / T_SU, rt = u - b * T_SU;
        M = NSU; TK = TK_SU;
        A = adj_su + (size_t)b * NSU * NSU;
        Yf = y1tf + Y1F_SU(b);
        AbT = abf8 + SU_BASE8 + (size_t)u * TSZ8_SU;
        Y2b = y2f8 + Y2F8_SU(b);
        row0 = rt * 16;
    }

    const float* Ar[4];
    #pragma unroll
    for (int rr = 0; rr < 4; ++rr) {
        int r = row0 + w * 4 + rr;
        if (r >= M) r = M - 1;
        Ar[rr] = A + (size_t)r * M;
    }

    const int c4 = lane * 4;
    const int k64i = c4 >> 6;
    const int c63 = c4 & 63;
    const int rxor = (l15 & 7) << 3;

    f32x4 acc = {0.f, 0.f, 0.f, 0.f};
    const int G = (TK + 3) >> 2;

    float4 avA[4], avB[4];
    // prologue: group 0 -> avA, group 1 -> avB
    #pragma unroll
    for (int rr = 0; rr < 4; ++rr) {
        float4 v = make_float4(0.f, 0.f, 0.f, 0.f);
        if (c4 < M) v = *(const float4*)(Ar[rr] + c4);
        avA[rr] = v;
    }
    #pragma unroll
    for (int rr = 0; rr < 4; ++rr) {
        const int col = 256 + c4;
        float4 v = make_float4(0.f, 0.f, 0.f, 0.f);
        if (G > 1 && col < M) v = *(const float4*)(Ar[rr] + col);
        avB[rr] = v;
    }

#define ITER(AV, PARITY, gg) do { \
    const int ch_ = (gg) * 4; \
    const int nk_ = (TK - ch_ < 4) ? (TK - ch_) : 4; \
    unsigned short* buf_ = &AL[PARITY][0]; \
    _Pragma("unroll") \
    for (int rr = 0; rr < 4; ++rr) { \
        const int r_ = w * 4 + rr; \
        const unsigned int u0_ = pkbf(AV[rr].x, AV[rr].y); \
        const unsigned int u1_ = pkbf(AV[rr].z, AV[rr].w); \
        const int sa_ = k64i * 1024 + r_ * 64 + (c63 ^ ((r_ & 7) << 3)); \
        *(uint2*)(&buf_[sa_]) = make_uint2(u0_, u1_); \
    } \
    __syncthreads(); \
    if ((gg) + 2 < G) { \
        const int cb2_ = ((gg) + 2) * 256; \
        _Pragma("unroll") \
        for (int rr = 0; rr < 4; ++rr) { \
            const int col_ = cb2_ + c4; \
            float4 v_ = make_float4(0.f, 0.f, 0.f, 0.f); \
            if (col_ < M) v_ = *(const float4*)(Ar[rr] + col_); \
            AV[rr] = v_; \
        } \
    } \
    _Pragma("unroll") \
    for (int j = 0; j < 4; ++j) { \
        if (j < nk_) { \
            const bf16x8 af0_ = *(const bf16x8*)(&buf_[j * 1024 + l15 * 64 + ((kq * 8) ^ rxor)]); \
            const bf16x8 af1_ = *(const bf16x8*)(&buf_[j * 1024 + l15 * 64 + ((32 + kq * 8) ^ rxor)]); \
            const unsigned short* bb_ = Yf + (size_t)(ch_ + j) * 4096 + w * 1024 + lane * 8; \
            const bf16x8 b0_ = *(const bf16x8*)(bb_); \
            const bf16x8 b1_ = *(const bf16x8*)(bb_ + 512); \
            acc = MFMA16(af0_, b0_, acc, 0, 0, 0); \
            acc = MFMA16(af1_, b1_, acc, 0, 0, 0); \
        } \
    } \
    if (w < nk_) { \
        const bf16x8 h0_ = *(const bf16x8*)(&buf_[w * 1024 + l15 * 64 + ((kq * 8) ^ rxor)]); \
        const bf16x8 h1_ = *(const bf16x8*)(&buf_[w * 1024 + l15 * 64 + ((32 + kq * 8) ^ rxor)]); \
        int q0_ = pk8lo(bf2f(h0_[0]), bf2f(h0_[1]), 0); q0_ = pk8hi(bf2f(h0_[2]), bf2f(h0_[3]), q0_); \
        int q1_ = pk8lo(bf2f(h0_[4]), bf2f(h0_[5]), 0); q1_ = pk8hi(bf2f(h0_[6]), bf2f(h0_[7]), q1_); \
        int q2_ = pk8lo(bf2f(h1_[0]), bf2f(h1_[1]), 0); q2_ = pk8hi(bf2f(h1_[2]), bf2f(h1_[3]), q2_); \
        int q3_ = pk8lo(bf2f(h1_[4]), bf2f(h1_[5]), 0); q3_ = pk8hi(bf2f(h1_[6]), bf2f(h1_[7]), q3_); \
        *(int4*)(AbT + (size_t)(ch_ + w) * 1024 + lane * 16) = make_int4(q0_, q1_, q2_, q3_); \
    } \
} while (0)

    int g = 0;
    while (g < G) {
        ITER(avA, 0, g);
        ++g;
        if (g < G) {
            ITER(avB, 1, g);
            ++g;
        }
    }
#undef ITER

    __syncthreads();
    // ---- fused mid: h = relu(acc + bc1) -> HL; y2 = h @ Wc2 -> y2f8 ----
    {
        const float bcv = bc1[w * 16 + l15];
        #pragma unroll
        for (int j = 0; j < 4; ++j) {
            const int r = kq * 4 + j;
            const int c = w * 16 + l15;
            HL[r * 64 + (c ^ ((r & 7) << 3))] = f2bf(fmaxf(acc[j] + bcv, 0.f));
        }
    }
    __syncthreads();
    if (w < 2) {
        const bf16x8 hf0 = *(const bf16x8*)(&HL[l15 * 64 + ((kq * 8) ^ rxor)]);
        const bf16x8 hf1 = *(const bf16x8*)(&HL[l15 * 64 + ((32 + kq * 8) ^ rxor)]);
        const unsigned short* wp = wc2t + (size_t)(w * 16 + l15) * 64 + kq * 8;
        const bf16x8 w0 = *(const bf16x8*)(wp);
        const bf16x8 w1 = *(const bf16x8*)(wp + 32);
        f32x4 m = {0.f, 0.f, 0.f, 0.f};
        m = MFMA16(hf0, w0, m, 0, 0, 0);
        m = MFMA16(hf1, w1, m, 0, 0, 0);
        const int mrow = row0 + kq * 4;
        const int chm = mrow >> 6, r6 = mrow & 63;
        const int halfm = r6 >> 5, kqqm = (r6 >> 3) & 3, e0 = r6 & 7;
        const int c = w * 16 + l15;
        int pk = pk8lo(m[0], m[1], 0); pk = pk8hi(m[2], m[3], pk);
        *(int*)(Y2b + (size_t)chm * 2048 + (c >> 4) * 1024
                + (kqqm * 16 + (c & 15)) * 16 + halfm * 8 + e0) = pk;
    }
}

// ---------------- conv2 partial: FP8 MFMA, 4-deep software pipeline ---------------------
__global__ __launch_bounds__(256) void conv2p_kernel(
    const unsigned char* __restrict__ abf8,
    const unsigned char* __restrict__ y2f8,
    float* __restrict__ p2)
{
    const int bid = (NBX_TOT - 1) - blockIdx.x;
    const int q = blockIdx.y;
    const int tid = threadIdx.x, lane = tid & 63, wid = tid >> 6;
    int tile0, cbeg, cend;
    const unsigned char* Yf2; const unsigned char* AbT;
    if (bid < 2 * NB64_SV) {
        int b = bid / NB64_SV, rb = bid - b * NB64_SV;
        Yf2 = y2f8 + Y2F8_SV(b);
        tile0 = b * T_SV + rb * 4;
        AbT = abf8 + (size_t)(tile0 + wid) * TSZ8_SV;
        cbeg = (q * NCH_SV) >> 3;
        cend = ((q + 1) * NCH_SV) >> 3;
    } else {
        int t = bid - 2 * NB64_SV;
        int b = t / NB64_SU, rb = t - b * NB64_SU;
        Yf2 = y2f8 + Y2F8_SU(b);
        int tsu = b * T_SU + rb * 4;
        tile0 = 2 * T_SV + tsu;
        AbT = abf8 + SU_BASE8 + (size_t)(tsu + wid) * TSZ8_SU;
        cbeg = (q * NCH_SU) >> 3;
        cend = ((q + 1) * NCH_SU) >> 3;
    }

    const int l15 = lane & 15, kq = lane >> 4;
    const unsigned char* Apl = AbT + (size_t)lane * 16;
    const unsigned char* Bpl = Yf2 + (size_t)lane * 16;

    f32x4 acc0 = {0.f,0.f,0.f,0.f}, acc1 = acc0;

    longx2 a0v, a1v, a2v, a3v;
    longx2 b00, b01, b10, b11, b20, b21, b30, b31;

#define LDSLOT(AV,B0,B1,ci) do { \
    int cc_ = (ci); if (cc_ >= cend) cc_ = cend - 1; \
    AV = *(const longx2*)(Apl + (size_t)cc_ * 1024); \
    const unsigned char* bb_ = Bpl + (size_t)cc_ * 2048; \
    B0 = *(const longx2*)(bb_); \
    B1 = *(const longx2*)(bb_ + 1024); } while (0)
#define CMP4(F,B0,B1) do { \
    acc0 = MFMA8(F[0], B0[0], acc0, 0, 0, 0); \
    acc1 = MFMA8(F[0], B1[0], acc1, 0, 0, 0); \
    acc0 = MFMA8(F[1], B0[1], acc0, 0, 0, 0); \
    acc1 = MFMA8(F[1], B1[1], acc1, 0, 0, 0); } while (0)

    if (cbeg < cend) {
        LDSLOT(a0v, b00, b01, cbeg);
        LDSLOT(a1v, b10, b11, cbeg + 1);
        LDSLOT(a2v, b20, b21, cbeg + 2);
        LDSLOT(a3v, b30, b31, cbeg + 3);
        int ch = cbeg;
        while (ch + 4 <= cend) {
            CMP4(a0v, b00, b01); LDSLOT(a0v, b00, b01, ch + 4);
            CMP4(a1v, b10, b11); LDSLOT(a1v, b10, b11, ch + 5);
            CMP4(a2v, b20, b21); LDSLOT(a2v, b20, b21, ch + 6);
            CMP4(a3v, b30, b31); LDSLOT(a3v, b30, b31, ch + 7);
            ch += 4;
        }
        if (ch     < cend) CMP4(a0v, b00, b01);
        if (ch + 1 < cend) CMP4(a1v, b10, b11);
        if (ch + 2 < cend) CMP4(a2v, b20, b21);
        if (ch + 3 < cend) CMP4(a3v, b30, b31);
    }
#undef LDSLOT
#undef CMP4

    float* Pp = p2 + ((size_t)q * TILES_TOT + tile0 + wid) * (16 * 32);
    #pragma unroll
    for (int j = 0; j < 4; ++j) {
        const int r = kq * 4 + j;
        Pp[r * 32 +      l15] = acc0[j];
        Pp[r * 32 + 16 + l15] = acc1[j];
    }
}

// ---------------- combine2: part[tile][c] = max_r (sum_q p2 + bc2 + init) ----------------
__global__ __launch_bounds__(256) void combine2_kernel(
    const float* __restrict__ p2, const float* __restrict__ bc2,
    const float* __restrict__ initb, float* __restrict__ part)
{
    const int idx = blockIdx.x * 256 + threadIdx.x;
    if (idx >= TILES_TOT * 32) return;
    const int gt = idx >> 5, c = idx & 31;
    int m0, M; const float* I;
    if (gt < 2 * T_SV) {
        int b = gt / T_SV;
        m0 = (gt - b * T_SV) * 16;
        M = NSV;
        I = initb + (size_t)ROWS_SU * 32 + (size_t)b * NSV * 32;
    } else {
        int t = gt - 2 * T_SV;
        int b = t / T_SU;
        m0 = (t - b * T_SU) * 16;
        M = NSU;
        I = initb + (size_t)b * NSU * 32;
    }
    const float* Q = p2 + (size_t)gt * 16 * 32 + c;
    const size_t QS = (size_t)TILES_TOT * 16 * 32;
    const float bb = bc2[c];
    float mx = NEG_INF;
    #pragma unroll
    for (int r = 0; r < 16; ++r) {
        const int m = m0 + r;
        if (m < M) {
            float s = bb + I[(size_t)m * 32 + c];
            #pragma unroll
            for (int qq = 0; qq < NH2; ++qq) s += Q[(size_t)qq * QS + r * 32];
            mx = fmaxf(mx, s);
        }
    }
    part[(size_t)gt * 32 + c] = mx;
}

// ---------------- head: pool-reduce + 4-layer MLP ----------------
__global__ __launch_bounds__(128) void head_kernel(
    const float* __restrict__ part,
    const float* __restrict__ Wfc2, const float* __restrict__ bfc2,
    const float* __restrict__ Wfc3, const float* __restrict__ bfc3,
    const float* __restrict__ Wfc4, const float* __restrict__ bfc4,
    const float* __restrict__ Wfc5, const float* __restrict__ bfc5,
    float* __restrict__ out)
{
    __shared__ float d[2][64];
    __shared__ float t1[2][32];
    __shared__ float t2[2][64];
    __shared__ float t3[2][32];
    const int tid = threadIdx.x;

    if (tid < 64) {
        const int b = tid >> 5, c = tid & 31;
        float m = NEG_INF;
        const float* ps = part + (size_t)(2 * T_SV + b * T_SU) * 32 + c;
        for (int i = 0; i < T_SU; ++i) m = fmaxf(m, ps[(size_t)i * 32]);
        d[b][c] = m;
        float m2 = NEG_INF;
        const float* pv = part + (size_t)b * T_SV * 32 + c;
        for (int i = 0; i < T_SV; ++i) m2 = fmaxf(m2, pv[(size_t)i * 32]);
        d[b][32 + c] = m2;
    }
    __syncthreads();
    if (tid < 64) {
        const int b = tid >> 5, c = tid & 31;
        float acc = bfc2[c];
        for (int f = 0; f < 64; ++f) acc += d[b][f] * Wfc2[f * 32 + c];
        t1[b][c] = fmaxf(acc, 0.f);
    }
    __syncthreads();
    {
        const int b = tid >> 6, c = tid & 63;
        float acc = bfc3[c];
        for (int f = 0; f < 32; ++f) acc += t1[b][f] * Wfc3[f * 64 + c];
        t2[b][c] = fmaxf(acc, 0.f);
    }
    __syncthreads();
    if (tid < 64) {
        const int b = tid >> 5, c = tid & 31;
        float acc = bfc4[c];
        for (int f = 0; f < 64; ++f) acc += t2[b][f] * Wfc4[f * 32 + c];
        t3[b][c] = fmaxf(acc, 0.f);
    }
    __syncthreads();
    if (tid < 2) {
        float acc = bfc5[0];
        for (int f = 0; f < 32; ++f) acc += t3[tid][f] * Wfc5[f];
        out[tid] = acc;
    }
}

extern "C" void kernel_launch(void* const* d_in, const int* in_sizes, int n_in,
                              void* d_out, int out_size, void* d_ws, size_t ws_size,
                              hipStream_t stream)
{
    const float* solute_adj   = (const float*)d_in[0];
    const float* solute_meth  = (const float*)d_in[1];
    const float* solvent_meth = (const float*)d_in[2];
    const float* solvent_adj  = (const float*)d_in[3];
    const float* W_fc1 = (const float*)d_in[4];
    const float* b_fc1 = (const float*)d_in[5];
    const float* W_c1  = (const float*)d_in[6];
    const float* b_c1  = (const float*)d_in[7];
    const float* W_c2  = (const float*)d_in[8];
    const float* b_c2  = (const float*)d_in[9];
    const float* W_fc2 = (const float*)d_in[10];
    const float* b_fc2 = (const float*)d_in[11];
    const float* W_fc3 = (const float*)d_in[12];
    const float* b_fc3 = (const float*)d_in[13];
    const float* W_fc4 = (const float*)d_in[14];
    const float* b_fc4 = (const float*)d_in[15];
    const float* W_fc5 = (const float*)d_in[16];
    const float* b_fc5 = (const float*)d_in[17];
    float* out = (float*)d_out;

    char* wsb = (char*)d_ws;
    size_t off = 0;
    unsigned short* y1tf = (unsigned short*)(wsb + off); off += 2850816;
    unsigned char*  y2f8 = (unsigned char*)(wsb + off);  off += 712704;
    unsigned short* wc2t = (unsigned short*)(wsb + off); off += 4096;
    float* initb         = (float*)(wsb + off);          off += 2820096;
    unsigned char* abf8  = (unsigned char*)(wsb + off);
    off += SU_BASE8 + (size_t)2 * T_SU * TSZ8_SU;
    off = (off + 15) & ~(size_t)15;
    float* p2            = (float*)(wsb + off);
    off += (size_t)NH2 * PADROWS * 32 * 4;
    float* part          = (float*)(wsb + off);          off += (size_t)TILES_TOT * 32 * 4;

    pre_kernel<<<dim3(PRE_BLKS + 1), dim3(256), 0, stream>>>(
        solute_meth, solvent_meth, W_c1, W_fc1, b_fc1, W_c2, y1tf, initb, wc2t);

    conv1f_kernel<<<dim3(TILES_TOT), dim3(256), 0, stream>>>(
        solute_adj, solvent_adj, y1tf, b_c1, wc2t, abf8, y2f8);

    conv2p_kernel<<<dim3(NBX_TOT, NH2), dim3(256), 0, stream>>>(abf8, y2f8, p2);

    combine2_kernel<<<dim3((TILES_TOT * 32 + 255) / 256), dim3(256), 0, stream>>>(
        p2, b_c2, initb, part);

    head_kernel<<<dim3(1), dim3(128), 0, stream>>>(
        part, W_fc2, b_fc2, W_fc3, b_fc3, W_fc4, b_fc4, W_fc5, b_fc5, out);
}